// Round 2
// baseline (404.490 us; speedup 1.0000x reference)
//
#include <hip/hip_runtime.h>

#define N_NEURONS 100000
#define MAX_DELAY 5
#define NSYN 5
#define T_STEPS 20
#define N_LGN 17400
#define N_BKG 100
#define E_REC 2000000
#define E_LGN 600000
#define E_BKG 200000
#define DT 1.0f

// ---------------- ws layout (floats) ----------------
// inp_buf   : [T][N][NSYN]      10,000,000   (layout: 5 syn values contiguous per neuron)
// zbuf      : [MAX_DELAY][N]       500,000   (circular: z(t) at slot t%5)
// psc_rise  : [NSYN][N]            500,000
// psc       : [NSYN][N]            500,000
// v         : [N]                  100,000
// r         : [N]                  100,000
// asc       : [N][2]               200,000
// counts    : int[32]                   32
// total floats = 11,900,032  (~45.4 MB)

__global__ void zero_ws(float* __restrict__ ws, long n4) {
    long i = (long)blockIdx.x * blockDim.x + threadIdx.x;
    long stride = (long)gridDim.x * blockDim.x;
    float4* p = (float4*)ws;
    float4 z = make_float4(0.f, 0.f, 0.f, 0.f);
    for (long j = i; j < n4; j += stride) p[j] = z;
}

// Precompute external (LGN + BKG) synaptic input for all timesteps.
// inp_buf layout [T][N][NSYN]: the 5 atomics per spiking edge hit ONE cache
// line (20 contiguous bytes) instead of 5 lines 400KB apart.
__global__ void ext_scatter(const float* __restrict__ lgn_spk, const float* __restrict__ bkg_spk,
                            const int* __restrict__ lgn_idx, const float* __restrict__ lgn_w,
                            const float* __restrict__ lgn_fac,
                            const int* __restrict__ bkg_idx, const float* __restrict__ bkg_w,
                            const float* __restrict__ bkg_fac,
                            float* __restrict__ inp_buf) {
    int e = blockIdx.x * blockDim.x + threadIdx.x;
    const int* idx; const float* wp; const float* fp; const float* spk; int ncols;
    if (e < E_LGN) {
        idx = lgn_idx; wp = lgn_w; fp = lgn_fac; spk = lgn_spk; ncols = N_LGN;
    } else {
        e -= E_LGN;
        if (e >= E_BKG) return;
        idx = bkg_idx; wp = bkg_w; fp = bkg_fac; spk = bkg_spk; ncols = N_BKG;
    }
    int post = idx[2 * e];
    int src  = idx[2 * e + 1];

    // Prefetch the edge's full spike row (20 independent L2 loads issued
    // back-to-back; latency overlapped).
    float s[T_STEPS];
#pragma unroll
    for (int t = 0; t < T_STEPS; ++t) s[t] = spk[t * ncols + src];

    float w  = wp[e];
    float f0 = fp[5*e], f1 = fp[5*e+1], f2 = fp[5*e+2], f3 = fp[5*e+3], f4 = fp[5*e+4];

#pragma unroll
    for (int t = 0; t < T_STEPS; ++t) {
        if (s[t] != 0.0f) {
            float sw = s[t] * w;
            float* base = inp_buf + ((size_t)t * N_NEURONS + post) * NSYN;
            atomicAdd(base,     sw * f0);
            atomicAdd(base + 1, sw * f1);
            atomicAdd(base + 2, sw * f2);
            atomicAdd(base + 3, sw * f3);
            atomicAdd(base + 4, sw * f4);
        }
    }
}

// Recurrent scatter for step t; gated on spike counts of the last MAX_DELAY steps.
__global__ void rec_scatter(const int* __restrict__ rec_idx, const float* __restrict__ rec_w,
                            const float* __restrict__ rec_fac,
                            const float* __restrict__ zbuf, const int* __restrict__ counts,
                            float* __restrict__ inp_t, int t) {
    int any = 0;
#pragma unroll
    for (int d = 1; d <= MAX_DELAY; ++d) {
        int j = t - d;
        if (j >= 0) any += counts[j];
    }
    if (any == 0) return;   // no spikes in the visible window -> nothing to do

    int tid = blockIdx.x * blockDim.x + threadIdx.x;
    int stride = gridDim.x * blockDim.x;
    for (int e = tid; e < E_REC; e += stride) {
        int post = rec_idx[2 * e];
        int col  = rec_idx[2 * e + 1];
        int d1   = col / N_NEURONS;          // delay - 1
        int pre  = col - d1 * N_NEURONS;
        int srcstep = t - 1 - d1;            // = t - delay
        if (srcstep < 0) continue;
        float s = zbuf[(srcstep % MAX_DELAY) * N_NEURONS + pre];
        if (s == 0.0f) continue;
        float sw = s * rec_w[e];
        float* base = inp_t + (size_t)post * NSYN;
        atomicAdd(base,     sw * rec_fac[5*e]);
        atomicAdd(base + 1, sw * rec_fac[5*e+1]);
        atomicAdd(base + 2, sw * rec_fac[5*e+2]);
        atomicAdd(base + 3, sw * rec_fac[5*e+3]);
        atomicAdd(base + 4, sw * rec_fac[5*e+4]);
    }
}

__global__ void neuron_update(float* __restrict__ zbuf,
                              float* __restrict__ psc_rise, float* __restrict__ psc,
                              float* __restrict__ v, float* __restrict__ r,
                              float* __restrict__ asc,
                              const float* __restrict__ inp_t,   // [N][NSYN]
                              const float* __restrict__ decay,
                              const float* __restrict__ current_factor,
                              const float* __restrict__ v_reset,
                              const float* __restrict__ t_ref,
                              const float* __restrict__ k,
                              const float* __restrict__ asc_amps,
                              const float* __restrict__ v_th,
                              const float* __restrict__ normalizer,
                              const float* __restrict__ g,
                              const float* __restrict__ syn_decay,
                              const float* __restrict__ psc_initial,
                              float* __restrict__ out, int* __restrict__ counts, int t) {
    int n = blockIdx.x * blockDim.x + threadIdx.x;
    bool fired = false;
    if (n < N_NEURONS) {
        float prev_z = (t == 0) ? 0.0f : zbuf[((t - 1) % MAX_DELAY) * N_NEURONS + n];

        float pr[NSYN], pc[NSYN];
        float ic = 0.0f;
#pragma unroll
        for (int s = 0; s < NSYN; ++s) {
            pr[s] = psc_rise[(size_t)s * N_NEURONS + n];
            pc[s] = psc[(size_t)s * N_NEURONS + n];
            ic += pc[s];            // input_current uses OLD psc
        }
        float a0 = asc[2 * n], a1 = asc[2 * n + 1];
        float c1 = ic + a0 + a1 + g[n];
        float dv = decay[n] * v[n] + current_factor[n] * c1;
        float nv = (prev_z > 0.5f) ? v_reset[n] : dv;
        float tr = t_ref[n];
        float nr = r[n] + prev_z * tr - DT;
        nr = fminf(fmaxf(nr, 0.0f), tr);
        float na0 = expf(-DT * k[2 * n])     * a0 + prev_z * asc_amps[2 * n];
        float na1 = expf(-DT * k[2 * n + 1]) * a1 + prev_z * asc_amps[2 * n + 1];

#pragma unroll
        for (int s = 0; s < NSYN; ++s) {
            float sd  = syn_decay[s];
            float npc = pc[s] * sd + DT * sd * pr[s];                 // uses OLD psc_rise
            float npr = pr[s] * sd + inp_t[(size_t)n * NSYN + s] * psc_initial[s];
            psc[(size_t)s * N_NEURONS + n]      = npc;
            psc_rise[(size_t)s * N_NEURONS + n] = npr;
        }
        v[n] = nv; r[n] = nr; asc[2 * n] = na0; asc[2 * n + 1] = na1;

        float vsc = (nv - v_th[n]) / normalizer[n];
        float z   = (vsc > 0.0f) ? 1.0f : 0.0f;
        float nz  = (nr > 0.0f) ? 0.0f : z;
        zbuf[(t % MAX_DELAY) * N_NEURONS + n] = nz;
        out[(size_t)t * N_NEURONS + n] = nz;
        fired = (nz != 0.0f);
    }
    unsigned long long m = __ballot(fired);
    if (m && (threadIdx.x & 63) == 0) atomicAdd(&counts[t], (int)__popcll(m));
}

extern "C" void kernel_launch(void* const* d_in, const int* in_sizes, int n_in,
                              void* d_out, int out_size, void* d_ws, size_t ws_size,
                              hipStream_t stream) {
    const float* lgn_spikes  = (const float*)d_in[0];
    const float* bkg_spikes  = (const float*)d_in[1];
    const int*   rec_indices = (const int*)  d_in[2];
    const float* rec_w       = (const float*)d_in[3];
    const float* rec_factors = (const float*)d_in[4];
    const int*   lgn_indices = (const int*)  d_in[5];
    const float* lgn_w       = (const float*)d_in[6];
    const float* lgn_factors = (const float*)d_in[7];
    const int*   bkg_indices = (const int*)  d_in[8];
    const float* bkg_w       = (const float*)d_in[9];
    const float* bkg_factors = (const float*)d_in[10];
    const float* decay       = (const float*)d_in[11];
    const float* current_factor = (const float*)d_in[12];
    const float* v_reset     = (const float*)d_in[13];
    const float* t_ref       = (const float*)d_in[14];
    const float* k           = (const float*)d_in[15];
    const float* asc_amps    = (const float*)d_in[16];
    const float* v_th        = (const float*)d_in[17];
    const float* normalizer  = (const float*)d_in[18];
    const float* gathered_g  = (const float*)d_in[19];
    const float* syn_decay   = (const float*)d_in[20];
    const float* psc_initial = (const float*)d_in[21];

    float* ws       = (float*)d_ws;
    float* inp_buf  = ws;
    float* zbuf     = inp_buf + (size_t)T_STEPS * NSYN * N_NEURONS;  // +10,000,000
    float* psc_rise = zbuf + (size_t)MAX_DELAY * N_NEURONS;          // +500,000
    float* psc      = psc_rise + (size_t)NSYN * N_NEURONS;           // +500,000
    float* vv       = psc + (size_t)NSYN * N_NEURONS;                // +500,000
    float* rr       = vv + N_NEURONS;
    float* asc      = rr + N_NEURONS;
    int*   counts   = (int*)(asc + 2 * (size_t)N_NEURONS);

    long total_floats = 11900032;  // includes counts (32 ints)
    zero_ws<<<2048, 256, 0, stream>>>(ws, total_floats / 4);

    ext_scatter<<<(E_LGN + E_BKG + 255) / 256, 256, 0, stream>>>(
        lgn_spikes, bkg_spikes,
        lgn_indices, lgn_w, lgn_factors,
        bkg_indices, bkg_w, bkg_factors,
        inp_buf);

    float* out = (float*)d_out;
    for (int t = 0; t < T_STEPS; ++t) {
        if (t > 0) {
            rec_scatter<<<2048, 256, 0, stream>>>(
                rec_indices, rec_w, rec_factors, zbuf, counts,
                inp_buf + (size_t)t * NSYN * N_NEURONS, t);
        }
        neuron_update<<<(N_NEURONS + 255) / 256, 256, 0, stream>>>(
            zbuf, psc_rise, psc, vv, rr, asc,
            inp_buf + (size_t)t * NSYN * N_NEURONS,
            decay, current_factor, v_reset, t_ref, k, asc_amps,
            v_th, normalizer, gathered_g, syn_decay, psc_initial,
            out, counts, t);
    }
}

// Round 3
// 283.285 us; speedup vs baseline: 1.4279x; 1.4279x over previous
//
#include <hip/hip_runtime.h>

#define N_NEURONS 100000
#define MAX_DELAY 5
#define NSYN 5
#define T_STEPS 20
#define N_LGN 17400
#define N_BKG 100
#define N_SRC (N_LGN + N_BKG)        // 17500
#define E_REC 2000000
#define E_LGN 600000
#define E_BKG 200000
#define E_EXT (E_LGN + E_BKG)        // 800000
#define DT 1.0f
#define NBLK_N 391                   // ceil(N/256)
#define TCHUNK 4
#define NTC (T_STEPS / TCHUNK)       // 5
#define SCALE_F 68719476736.0f       // 2^36
#define INV_SCALE (1.0 / 68719476736.0)

// ---------------- ws layout (float offsets) ----------------
#define OFF_INP   0u                  // [T][N][NSYN]  10,000,000
#define OFF_ZBUF  10000000u           // [MAX_DELAY][N]   500,000 (circular)
#define OFF_PSCR  10500000u           // [NSYN][N]        500,000
#define OFF_PSC   11000000u           // [NSYN][N]        500,000
#define OFF_V     11500000u           // [N]              100,000
#define OFF_R     11600000u           // [N]              100,000
#define OFF_ASC   11700000u           // [N][2]           200,000
#define OFF_CNTS  11900000u           // int[32]
#define OFF_CNT   11900032u           // int[N]           100,000
#define OFF_RP    12000032u           // int[N+1] pad     100,016
#define OFF_CUR   12100048u           // int[N]           100,000
#define OFF_BSUM  12200048u           // int[512]
#define OFF_PSRC  12200560u           // int[E_EXT]       800,000
#define OFF_PW    13000560u           // float[E_EXT]     800,000
#define OFF_PFAC  13800560u           // float[E_EXT*5] 4,000,000
#define OFF_SPKT  17800560u           // float[N_SRC*T]   350,000
#define TOTAL_F   18150560u           // 72.6 MB

__global__ void zero_range(float* __restrict__ p, long n4) {
    long i = (long)blockIdx.x * blockDim.x + threadIdx.x;
    long stride = (long)gridDim.x * blockDim.x;
    float4* q = (float4*)p;
    float4 z = make_float4(0.f, 0.f, 0.f, 0.f);
    for (long j = i; j < n4; j += stride) q[j] = z;
}

// spkT[srow][t] <- lgn/bkg spikes (t-major input)
__global__ void spk_transpose(const float* __restrict__ lgn, const float* __restrict__ bkg,
                              float* __restrict__ spkT) {
    int tid = blockIdx.x * blockDim.x + threadIdx.x;
    if (tid >= N_SRC * T_STEPS) return;
    int srow = tid / T_STEPS;
    int t    = tid - srow * T_STEPS;
    float v = (srow < N_LGN) ? lgn[t * N_LGN + srow] : bkg[t * N_BKG + (srow - N_LGN)];
    spkT[tid] = v;
}

__global__ void csr_count(const int* __restrict__ lgn_idx, const int* __restrict__ bkg_idx,
                          int* __restrict__ cnt) {
    int e = blockIdx.x * blockDim.x + threadIdx.x;
    if (e >= E_EXT) return;
    int post = (e < E_LGN) ? lgn_idx[2 * e] : bkg_idx[2 * (e - E_LGN)];
    atomicAdd(&cnt[post], 1);
}

__global__ void scanA(const int* __restrict__ cnt, int* __restrict__ rp, int* __restrict__ bsum) {
    __shared__ int sh[256];
    int i = blockIdx.x * 256 + threadIdx.x;
    int v = (i < N_NEURONS) ? cnt[i] : 0;
    sh[threadIdx.x] = v;
    __syncthreads();
    for (int off = 1; off < 256; off <<= 1) {
        int t = (threadIdx.x >= off) ? sh[threadIdx.x - off] : 0;
        __syncthreads();
        sh[threadIdx.x] += t;
        __syncthreads();
    }
    if (i < N_NEURONS) rp[i] = sh[threadIdx.x] - v;   // exclusive within block
    if (threadIdx.x == 255) bsum[blockIdx.x] = sh[255];
}

__global__ void scanB(int* __restrict__ bsum) {
    __shared__ int sh[512];
    int v = (threadIdx.x < NBLK_N) ? bsum[threadIdx.x] : 0;
    sh[threadIdx.x] = v;
    __syncthreads();
    for (int off = 1; off < 512; off <<= 1) {
        int t = (threadIdx.x >= off) ? sh[threadIdx.x - off] : 0;
        __syncthreads();
        sh[threadIdx.x] += t;
        __syncthreads();
    }
    if (threadIdx.x < NBLK_N) bsum[threadIdx.x] = sh[threadIdx.x] - v;  // exclusive block offsets
}

__global__ void scanC(int* __restrict__ rp, int* __restrict__ cur, const int* __restrict__ bsum) {
    int i = blockIdx.x * 256 + threadIdx.x;
    if (i < N_NEURONS) {
        int v = rp[i] + bsum[blockIdx.x];
        rp[i] = v;
        cur[i] = v;
    }
    if (i == 0) rp[N_NEURONS] = E_EXT;
}

// Reorder edge payload into CSR slot order (sequential gather reads later).
__global__ void csr_fill(const int* __restrict__ lgn_idx, const float* __restrict__ lgn_w,
                         const float* __restrict__ lgn_fac,
                         const int* __restrict__ bkg_idx, const float* __restrict__ bkg_w,
                         const float* __restrict__ bkg_fac,
                         int* __restrict__ cur, int* __restrict__ psrc,
                         float* __restrict__ pw, float* __restrict__ pfac) {
    int e = blockIdx.x * blockDim.x + threadIdx.x;
    if (e >= E_EXT) return;
    int post, srow; float w; const float* f;
    if (e < E_LGN) {
        post = lgn_idx[2 * e]; srow = lgn_idx[2 * e + 1];
        w = lgn_w[e]; f = lgn_fac + 5 * (size_t)e;
    } else {
        int b = e - E_LGN;
        post = bkg_idx[2 * b]; srow = N_LGN + bkg_idx[2 * b + 1];
        w = bkg_w[b]; f = bkg_fac + 5 * (size_t)b;
    }
    int slot = atomicAdd(&cur[post], 1);
    psrc[slot] = srow;
    pw[slot] = w;
    float* d = pfac + 5 * (size_t)slot;
    d[0] = f[0]; d[1] = f[1]; d[2] = f[2]; d[3] = f[3]; d[4] = f[4];
}

// Atomic-free gather: thread = (t-chunk, neuron). int64 fixed-point accumulation
// makes the result independent of CSR slot order (deterministic across replays).
__global__ void ext_gather(const int* __restrict__ rp, const int* __restrict__ psrc,
                           const float* __restrict__ pw, const float* __restrict__ pfac,
                           const float* __restrict__ spkT, float* __restrict__ inp) {
    int tc = blockIdx.x / NBLK_N;
    int n  = (blockIdx.x % NBLK_N) * 256 + threadIdx.x;
    if (n >= N_NEURONS) return;
    int e0 = rp[n], e1 = rp[n + 1];
    long long acc[TCHUNK][NSYN] = {};
    for (int e = e0; e < e1; ++e) {
        const float4 s4 = *(const float4*)(spkT + (size_t)psrc[e] * T_STEPS + tc * TCHUNK);
        if (s4.x == 0.f && s4.y == 0.f && s4.z == 0.f && s4.w == 0.f) continue;
        float w = pw[e];
        const float* f = pfac + 5 * (size_t)e;
        long long q[NSYN];
#pragma unroll
        for (int s = 0; s < NSYN; ++s) q[s] = (long long)(w * f[s] * SCALE_F);
        float ss[TCHUNK] = {s4.x, s4.y, s4.z, s4.w};
#pragma unroll
        for (int ti = 0; ti < TCHUNK; ++ti) {
            if (ss[ti] != 0.0f) {
#pragma unroll
                for (int s = 0; s < NSYN; ++s) acc[ti][s] += q[s];
            }
        }
    }
#pragma unroll
    for (int ti = 0; ti < TCHUNK; ++ti) {
        int t = tc * TCHUNK + ti;
        float* o = inp + ((size_t)t * N_NEURONS + n) * NSYN;
#pragma unroll
        for (int s = 0; s < NSYN; ++s) o[s] = (float)((double)acc[ti][s] * INV_SCALE);
    }
}

// Fallback (small ws): round-2 style atomic scatter.
__global__ void ext_scatter(const float* __restrict__ lgn_spk, const float* __restrict__ bkg_spk,
                            const int* __restrict__ lgn_idx, const float* __restrict__ lgn_w,
                            const float* __restrict__ lgn_fac,
                            const int* __restrict__ bkg_idx, const float* __restrict__ bkg_w,
                            const float* __restrict__ bkg_fac,
                            float* __restrict__ inp_buf) {
    int e = blockIdx.x * blockDim.x + threadIdx.x;
    const int* idx; const float* wp; const float* fp; const float* spk; int ncols;
    if (e < E_LGN) {
        idx = lgn_idx; wp = lgn_w; fp = lgn_fac; spk = lgn_spk; ncols = N_LGN;
    } else {
        e -= E_LGN;
        if (e >= E_BKG) return;
        idx = bkg_idx; wp = bkg_w; fp = bkg_fac; spk = bkg_spk; ncols = N_BKG;
    }
    int post = idx[2 * e];
    int src  = idx[2 * e + 1];
    float s[T_STEPS];
#pragma unroll
    for (int t = 0; t < T_STEPS; ++t) s[t] = spk[t * ncols + src];
    float w  = wp[e];
    float f0 = fp[5*e], f1 = fp[5*e+1], f2 = fp[5*e+2], f3 = fp[5*e+3], f4 = fp[5*e+4];
#pragma unroll
    for (int t = 0; t < T_STEPS; ++t) {
        if (s[t] != 0.0f) {
            float sw = s[t] * w;
            float* base = inp_buf + ((size_t)t * N_NEURONS + post) * NSYN;
            atomicAdd(base,     sw * f0);
            atomicAdd(base + 1, sw * f1);
            atomicAdd(base + 2, sw * f2);
            atomicAdd(base + 3, sw * f3);
            atomicAdd(base + 4, sw * f4);
        }
    }
}

// Recurrent scatter for step t; gated on spike counts of the last MAX_DELAY steps.
__global__ void rec_scatter(const int* __restrict__ rec_idx, const float* __restrict__ rec_w,
                            const float* __restrict__ rec_fac,
                            const float* __restrict__ zbuf, const int* __restrict__ counts,
                            float* __restrict__ inp_t, int t) {
    int any = 0;
#pragma unroll
    for (int d = 1; d <= MAX_DELAY; ++d) {
        int j = t - d;
        if (j >= 0) any += counts[j];
    }
    if (any == 0) return;

    int tid = blockIdx.x * blockDim.x + threadIdx.x;
    int stride = gridDim.x * blockDim.x;
    for (int e = tid; e < E_REC; e += stride) {
        int post = rec_idx[2 * e];
        int col  = rec_idx[2 * e + 1];
        int d1   = col / N_NEURONS;          // delay - 1
        int pre  = col - d1 * N_NEURONS;
        int srcstep = t - 1 - d1;            // = t - delay
        if (srcstep < 0) continue;
        float s = zbuf[(srcstep % MAX_DELAY) * N_NEURONS + pre];
        if (s == 0.0f) continue;
        float sw = s * rec_w[e];
        float* base = inp_t + (size_t)post * NSYN;
        atomicAdd(base,     sw * rec_fac[5*e]);
        atomicAdd(base + 1, sw * rec_fac[5*e+1]);
        atomicAdd(base + 2, sw * rec_fac[5*e+2]);
        atomicAdd(base + 3, sw * rec_fac[5*e+3]);
        atomicAdd(base + 4, sw * rec_fac[5*e+4]);
    }
}

__global__ void neuron_update(float* __restrict__ zbuf,
                              float* __restrict__ psc_rise, float* __restrict__ psc,
                              float* __restrict__ v, float* __restrict__ r,
                              float* __restrict__ asc,
                              const float* __restrict__ inp_t,   // [N][NSYN]
                              const float* __restrict__ decay,
                              const float* __restrict__ current_factor,
                              const float* __restrict__ v_reset,
                              const float* __restrict__ t_ref,
                              const float* __restrict__ k,
                              const float* __restrict__ asc_amps,
                              const float* __restrict__ v_th,
                              const float* __restrict__ normalizer,
                              const float* __restrict__ g,
                              const float* __restrict__ syn_decay,
                              const float* __restrict__ psc_initial,
                              float* __restrict__ out, int* __restrict__ counts, int t) {
    int n = blockIdx.x * blockDim.x + threadIdx.x;
    bool fired = false;
    if (n < N_NEURONS) {
        float prev_z = (t == 0) ? 0.0f : zbuf[((t - 1) % MAX_DELAY) * N_NEURONS + n];

        float pr[NSYN], pc[NSYN];
        float ic = 0.0f;
#pragma unroll
        for (int s = 0; s < NSYN; ++s) {
            pr[s] = psc_rise[(size_t)s * N_NEURONS + n];
            pc[s] = psc[(size_t)s * N_NEURONS + n];
            ic += pc[s];            // input_current uses OLD psc
        }
        float a0 = asc[2 * n], a1 = asc[2 * n + 1];
        float c1 = ic + a0 + a1 + g[n];
        float dv = decay[n] * v[n] + current_factor[n] * c1;
        float nv = (prev_z > 0.5f) ? v_reset[n] : dv;
        float tr = t_ref[n];
        float nr = r[n] + prev_z * tr - DT;
        nr = fminf(fmaxf(nr, 0.0f), tr);
        float na0 = expf(-DT * k[2 * n])     * a0 + prev_z * asc_amps[2 * n];
        float na1 = expf(-DT * k[2 * n + 1]) * a1 + prev_z * asc_amps[2 * n + 1];

#pragma unroll
        for (int s = 0; s < NSYN; ++s) {
            float sd  = syn_decay[s];
            float npc = pc[s] * sd + DT * sd * pr[s];                 // uses OLD psc_rise
            float npr = pr[s] * sd + inp_t[(size_t)n * NSYN + s] * psc_initial[s];
            psc[(size_t)s * N_NEURONS + n]      = npc;
            psc_rise[(size_t)s * N_NEURONS + n] = npr;
        }
        v[n] = nv; r[n] = nr; asc[2 * n] = na0; asc[2 * n + 1] = na1;

        float vsc = (nv - v_th[n]) / normalizer[n];
        float z   = (vsc > 0.0f) ? 1.0f : 0.0f;
        float nz  = (nr > 0.0f) ? 0.0f : z;
        zbuf[(t % MAX_DELAY) * N_NEURONS + n] = nz;
        out[(size_t)t * N_NEURONS + n] = nz;
        fired = (nz != 0.0f);
    }
    unsigned long long m = __ballot(fired);
    if (m && (threadIdx.x & 63) == 0) atomicAdd(&counts[t], (int)__popcll(m));
}

extern "C" void kernel_launch(void* const* d_in, const int* in_sizes, int n_in,
                              void* d_out, int out_size, void* d_ws, size_t ws_size,
                              hipStream_t stream) {
    const float* lgn_spikes  = (const float*)d_in[0];
    const float* bkg_spikes  = (const float*)d_in[1];
    const int*   rec_indices = (const int*)  d_in[2];
    const float* rec_w       = (const float*)d_in[3];
    const float* rec_factors = (const float*)d_in[4];
    const int*   lgn_indices = (const int*)  d_in[5];
    const float* lgn_w       = (const float*)d_in[6];
    const float* lgn_factors = (const float*)d_in[7];
    const int*   bkg_indices = (const int*)  d_in[8];
    const float* bkg_w       = (const float*)d_in[9];
    const float* bkg_factors = (const float*)d_in[10];
    const float* decay       = (const float*)d_in[11];
    const float* current_factor = (const float*)d_in[12];
    const float* v_reset     = (const float*)d_in[13];
    const float* t_ref       = (const float*)d_in[14];
    const float* k           = (const float*)d_in[15];
    const float* asc_amps    = (const float*)d_in[16];
    const float* v_th        = (const float*)d_in[17];
    const float* normalizer  = (const float*)d_in[18];
    const float* gathered_g  = (const float*)d_in[19];
    const float* syn_decay   = (const float*)d_in[20];
    const float* psc_initial = (const float*)d_in[21];

    float* ws       = (float*)d_ws;
    float* inp_buf  = ws + OFF_INP;
    float* zbuf     = ws + OFF_ZBUF;
    float* psc_rise = ws + OFF_PSCR;
    float* psc      = ws + OFF_PSC;
    float* vv       = ws + OFF_V;
    float* rr       = ws + OFF_R;
    float* asc      = ws + OFF_ASC;
    int*   counts   = (int*)(ws + OFF_CNTS);
    int*   cnt      = (int*)(ws + OFF_CNT);
    int*   rp       = (int*)(ws + OFF_RP);
    int*   cur      = (int*)(ws + OFF_CUR);
    int*   bsum     = (int*)(ws + OFF_BSUM);
    int*   psrc     = (int*)(ws + OFF_PSRC);
    float* pw       = ws + OFF_PW;
    float* pfac     = ws + OFF_PFAC;
    float* spkT     = ws + OFF_SPKT;

    bool big = ws_size >= (size_t)TOTAL_F * 4;

    if (big) {
        // zero zbuf..cnt (state + counters): 2,000,032 floats
        zero_range<<<512, 256, 0, stream>>>(zbuf, 2000032 / 4);
        spk_transpose<<<(N_SRC * T_STEPS + 255) / 256, 256, 0, stream>>>(lgn_spikes, bkg_spikes, spkT);
        csr_count<<<(E_EXT + 255) / 256, 256, 0, stream>>>(lgn_indices, bkg_indices, cnt);
        scanA<<<NBLK_N, 256, 0, stream>>>(cnt, rp, bsum);
        scanB<<<1, 512, 0, stream>>>(bsum);
        scanC<<<NBLK_N, 256, 0, stream>>>(rp, cur, bsum);
        csr_fill<<<(E_EXT + 255) / 256, 256, 0, stream>>>(
            lgn_indices, lgn_w, lgn_factors, bkg_indices, bkg_w, bkg_factors,
            cur, psrc, pw, pfac);
        ext_gather<<<NTC * NBLK_N, 256, 0, stream>>>(rp, psrc, pw, pfac, spkT, inp_buf);
    } else {
        // Fallback: zero inp+state+counts, then atomic scatter (round-2 path).
        zero_range<<<2048, 256, 0, stream>>>(ws, 11900064 / 4);
        ext_scatter<<<(E_EXT + 255) / 256, 256, 0, stream>>>(
            lgn_spikes, bkg_spikes,
            lgn_indices, lgn_w, lgn_factors,
            bkg_indices, bkg_w, bkg_factors,
            inp_buf);
    }

    float* out = (float*)d_out;
    for (int t = 0; t < T_STEPS; ++t) {
        if (t > 0) {
            rec_scatter<<<1024, 256, 0, stream>>>(
                rec_indices, rec_w, rec_factors, zbuf, counts,
                inp_buf + (size_t)t * NSYN * N_NEURONS, t);
        }
        neuron_update<<<(N_NEURONS + 255) / 256, 256, 0, stream>>>(
            zbuf, psc_rise, psc, vv, rr, asc,
            inp_buf + (size_t)t * NSYN * N_NEURONS,
            decay, current_factor, v_reset, t_ref, k, asc_amps,
            v_th, normalizer, gathered_g, syn_decay, psc_initial,
            out, counts, t);
    }
}

// Round 4
// 131.227 us; speedup vs baseline: 3.0824x; 2.1587x over previous
//
#include <hip/hip_runtime.h>

#define N_NEURONS 100000
#define MAX_DELAY 5
#define NSYN 5
#define T_STEPS 20
#define N_LGN 17400
#define N_BKG 100
#define N_SRC (N_LGN + N_BKG)        // 17500
#define E_REC 2000000
#define E_LGN 600000
#define E_BKG 200000
#define E_EXT (E_LGN + E_BKG)        // 800000
#define DT 1.0f
#define NBLK_N 391                   // ceil(N/256)
#define SCALE_F 16777216.0f          // 2^24 fixed-point (order-invariant accumulation)
#define INV_SCALE (1.0 / 16777216.0)

// ---------------- ws layout (4-byte units) ----------------
#define OFF_FLAG  0u                 // int[32]   : [0]=any-spike flag
#define OFF_CNT   32u                // int[N]    : per-post edge counts
#define OFF_RP    100064u            // int[N+1]  : CSR row pointers
#define OFF_CUR   200096u            // int[N]    : fill cursors
#define OFF_BSUM  300128u            // int[512]  : scan block sums
#define OFF_BITS  300672u            // uint[N_SRC]: 20-bit spike masks
#define OFF_PSRC  318208u            // int[E_EXT]: src row per CSR slot
#define OFF_PAY   1120000u           // float[E_EXT*8]: {w,f0..f4,pad,pad} (32B aligned)
#define OFF_ZBUF  (1120000u + 6400000u)   // 7520000  float[5*N]   (fallback only)
#define OFF_V     8020000u           // float[N]   (fallback only)
#define OFF_R     8120000u
#define OFF_ASC   8220000u           // float[2N]
#define OFF_PR    8420000u           // float[5N]
#define OFF_PC    8920000u           // float[5N]
#define OFF_INPI  9420000u           // int[5N]
#define TOTAL_F   9920000u           // ~39.7 MB (ws proven >= 72.6 MB in round 3)

__global__ void zero_small(int* __restrict__ p, int n) {
    int i = blockIdx.x * blockDim.x + threadIdx.x;
    if (i < n) p[i] = 0;
}

// 20-bit spike mask per external source row.
__global__ void spk_bits_k(const float* __restrict__ lgn, const float* __restrict__ bkg,
                           unsigned* __restrict__ bits) {
    int i = blockIdx.x * blockDim.x + threadIdx.x;
    if (i >= N_SRC) return;
    unsigned b = 0;
    if (i < N_LGN) {
#pragma unroll
        for (int t = 0; t < T_STEPS; ++t)
            if (lgn[t * N_LGN + i] != 0.0f) b |= (1u << t);
    } else {
        int j = i - N_LGN;
#pragma unroll
        for (int t = 0; t < T_STEPS; ++t)
            if (bkg[t * N_BKG + j] != 0.0f) b |= (1u << t);
    }
    bits[i] = b;
}

__global__ void csr_count(const int* __restrict__ lgn_idx, const int* __restrict__ bkg_idx,
                          int* __restrict__ cnt) {
    int e = blockIdx.x * blockDim.x + threadIdx.x;
    if (e >= E_EXT) return;
    int post = (e < E_LGN) ? lgn_idx[2 * e] : bkg_idx[2 * (e - E_LGN)];
    atomicAdd(&cnt[post], 1);
}

__global__ void scanA(const int* __restrict__ cnt, int* __restrict__ rp, int* __restrict__ bsum) {
    __shared__ int sh[256];
    int i = blockIdx.x * 256 + threadIdx.x;
    int v = (i < N_NEURONS) ? cnt[i] : 0;
    sh[threadIdx.x] = v;
    __syncthreads();
    for (int off = 1; off < 256; off <<= 1) {
        int t = (threadIdx.x >= off) ? sh[threadIdx.x - off] : 0;
        __syncthreads();
        sh[threadIdx.x] += t;
        __syncthreads();
    }
    if (i < N_NEURONS) rp[i] = sh[threadIdx.x] - v;
    if (threadIdx.x == 255) bsum[blockIdx.x] = sh[255];
}

__global__ void scanB(int* __restrict__ bsum) {
    __shared__ int sh[512];
    int v = (threadIdx.x < NBLK_N) ? bsum[threadIdx.x] : 0;
    sh[threadIdx.x] = v;
    __syncthreads();
    for (int off = 1; off < 512; off <<= 1) {
        int t = (threadIdx.x >= off) ? sh[threadIdx.x - off] : 0;
        __syncthreads();
        sh[threadIdx.x] += t;
        __syncthreads();
    }
    if (threadIdx.x < NBLK_N) bsum[threadIdx.x] = sh[threadIdx.x] - v;
}

__global__ void scanC(int* __restrict__ rp, int* __restrict__ cur, const int* __restrict__ bsum) {
    int i = blockIdx.x * 256 + threadIdx.x;
    if (i < N_NEURONS) {
        int v = rp[i] + bsum[blockIdx.x];
        rp[i] = v;
        cur[i] = v;
    }
    if (i == 0) rp[N_NEURONS] = E_EXT;
}

// Reorder payload into CSR slot order. Packed 32B struct per slot:
// pay[8*slot] = {w, f0, f1, f2, f3, f4, 0, 0}; psrc[slot] = source row.
__global__ void csr_fill(const int* __restrict__ lgn_idx, const float* __restrict__ lgn_w,
                         const float* __restrict__ lgn_fac,
                         const int* __restrict__ bkg_idx, const float* __restrict__ bkg_w,
                         const float* __restrict__ bkg_fac,
                         int* __restrict__ cur, int* __restrict__ psrc,
                         float* __restrict__ pay) {
    int e = blockIdx.x * blockDim.x + threadIdx.x;
    if (e >= E_EXT) return;
    int post, srow; float w; const float* f;
    if (e < E_LGN) {
        int2 pc2 = ((const int2*)lgn_idx)[e];
        post = pc2.x; srow = pc2.y;
        w = lgn_w[e]; f = lgn_fac + 5 * (size_t)e;
    } else {
        int b = e - E_LGN;
        int2 pc2 = ((const int2*)bkg_idx)[b];
        post = pc2.x; srow = N_LGN + pc2.y;
        w = bkg_w[b]; f = bkg_fac + 5 * (size_t)b;
    }
    int slot = atomicAdd(&cur[post], 1);
    psrc[slot] = srow;
    float4 a = make_float4(w, f[0], f[1], f[2]);
    float4 b4 = make_float4(f[3], f[4], 0.0f, 0.0f);
    float4* d = (float4*)(pay + 8 * (size_t)slot);
    d[0] = a;
    d[1] = b4;
}

// Fused: per-neuron external-input gather (int32 fixed-point, order-invariant)
// + full 20-step GLIF scan in registers, assuming zero recurrent input.
// Sound because the FIRST true spike is recurrence-free: if this kernel sees
// no spikes anywhere, its output is exact; else it raises `flag` and
// fallback_redo recomputes everything.
__global__ void __launch_bounds__(256) fused_scan(
    const int* __restrict__ rp, const int* __restrict__ psrc,
    const float* __restrict__ pay, const unsigned* __restrict__ bits,
    const float* __restrict__ decay, const float* __restrict__ cf,
    const float* __restrict__ vres, const float* __restrict__ tref,
    const float* __restrict__ kk, const float* __restrict__ aamps,
    const float* __restrict__ vth, const float* __restrict__ norm,
    const float* __restrict__ gg, const float* __restrict__ sdec,
    const float* __restrict__ psci,
    float* __restrict__ out, int* __restrict__ flag)
{
    int n = blockIdx.x * 256 + threadIdx.x;
    if (n >= N_NEURONS) return;

    int acc[T_STEPS][NSYN] = {};
    int e1 = rp[n + 1];
    for (int e = rp[n]; e < e1; ++e) {
        unsigned b = bits[psrc[e]];
        if (!b) continue;                       // source never fires: skip payload
        const float4* P = (const float4*)(pay + 8 * (size_t)e);
        float4 pa = P[0];
        float4 pb = P[1];
        float w = pa.x;
        int q0 = __float2int_rn(w * pa.y * SCALE_F);
        int q1 = __float2int_rn(w * pa.z * SCALE_F);
        int q2 = __float2int_rn(w * pa.w * SCALE_F);
        int q3 = __float2int_rn(w * pb.x * SCALE_F);
        int q4 = __float2int_rn(w * pb.y * SCALE_F);
#pragma unroll
        for (int t = 0; t < T_STEPS; ++t) {
            if ((b >> t) & 1u) {
                acc[t][0] += q0; acc[t][1] += q1; acc[t][2] += q2;
                acc[t][3] += q3; acc[t][4] += q4;
            }
        }
    }

    float dec = decay[n], cfa = cf[n], vr = vres[n], tr = tref[n];
    float ek0 = expf(-DT * kk[2 * n]), ek1 = expf(-DT * kk[2 * n + 1]);
    float aa0 = aamps[2 * n], aa1 = aamps[2 * n + 1];
    float vt = vth[n], nm = norm[n], g = gg[n];
    float sd0 = sdec[0], sd1 = sdec[1], sd2 = sdec[2], sd3 = sdec[3], sd4 = sdec[4];
    float pi0 = psci[0], pi1 = psci[1], pi2 = psci[2], pi3 = psci[3], pi4 = psci[4];

    float pr0 = 0.f, pr1 = 0.f, pr2 = 0.f, pr3 = 0.f, pr4 = 0.f;
    float pc0 = 0.f, pc1 = 0.f, pc2 = 0.f, pc3 = 0.f, pc4 = 0.f;
    float v = 0.f, r = 0.f, a0 = 0.f, a1 = 0.f, pz = 0.f;
    bool anyf = false;

#pragma unroll
    for (int t = 0; t < T_STEPS; ++t) {
        float ic = pc0 + pc1 + pc2 + pc3 + pc4;      // input_current uses OLD psc
        float c1 = ic + a0 + a1 + g;
        float dv = dec * v + cfa * c1;
        float nv = (pz > 0.5f) ? vr : dv;
        float nr = r + pz * tr - DT;
        nr = fminf(fmaxf(nr, 0.0f), tr);
        a0 = ek0 * a0 + pz * aa0;
        a1 = ek1 * a1 + pz * aa1;

        float i0 = (float)((double)acc[t][0] * INV_SCALE);
        float i1 = (float)((double)acc[t][1] * INV_SCALE);
        float i2 = (float)((double)acc[t][2] * INV_SCALE);
        float i3 = (float)((double)acc[t][3] * INV_SCALE);
        float i4 = (float)((double)acc[t][4] * INV_SCALE);

        float np0 = pc0 * sd0 + DT * sd0 * pr0;      // new psc from OLD psc_rise
        float np1 = pc1 * sd1 + DT * sd1 * pr1;
        float np2 = pc2 * sd2 + DT * sd2 * pr2;
        float np3 = pc3 * sd3 + DT * sd3 * pr3;
        float np4 = pc4 * sd4 + DT * sd4 * pr4;
        pr0 = pr0 * sd0 + i0 * pi0;  pc0 = np0;
        pr1 = pr1 * sd1 + i1 * pi1;  pc1 = np1;
        pr2 = pr2 * sd2 + i2 * pi2;  pc2 = np2;
        pr3 = pr3 * sd3 + i3 * pi3;  pc3 = np3;
        pr4 = pr4 * sd4 + i4 * pi4;  pc4 = np4;

        v = nv; r = nr;
        float vsc = (nv - vt) / nm;
        float z = (vsc > 0.0f) ? 1.0f : 0.0f;
        float nz = (nr > 0.0f) ? 0.0f : z;
        out[(size_t)t * N_NEURONS + n] = nz;
        pz = nz;
        anyf = anyf || (nz != 0.0f);
    }
    if (anyf) atomicAdd(flag, 1);
}

// Exact coupled redo inside ONE workgroup (grid sync == __syncthreads()).
// Runs only if fused_scan detected any spike; early-exits (~2us) otherwise.
__global__ void __launch_bounds__(1024) fallback_redo(
    const int* __restrict__ rp, const int* __restrict__ psrc,
    const float* __restrict__ pay, const unsigned* __restrict__ bits,
    const int* __restrict__ rec_idx, const float* __restrict__ rec_w,
    const float* __restrict__ rec_fac,
    const float* __restrict__ decay, const float* __restrict__ cf,
    const float* __restrict__ vres, const float* __restrict__ tref,
    const float* __restrict__ kk, const float* __restrict__ aamps,
    const float* __restrict__ vth, const float* __restrict__ norm,
    const float* __restrict__ gg, const float* __restrict__ sdec,
    const float* __restrict__ psci,
    float* __restrict__ zbuf, float* __restrict__ vv, float* __restrict__ rr,
    float* __restrict__ asc, float* __restrict__ pra, float* __restrict__ pca,
    int* __restrict__ inpi, float* __restrict__ out, const int* __restrict__ flag)
{
    if (flag[0] == 0) return;
    int tid = threadIdx.x;
    for (int i = tid; i < N_NEURONS; i += 1024) { vv[i] = 0.f; rr[i] = 0.f; }
    for (int i = tid; i < 2 * N_NEURONS; i += 1024) asc[i] = 0.f;
    for (int i = tid; i < NSYN * N_NEURONS; i += 1024) { pra[i] = 0.f; pca[i] = 0.f; }
    for (int i = tid; i < MAX_DELAY * N_NEURONS; i += 1024) zbuf[i] = 0.f;
    __syncthreads();

    for (int t = 0; t < T_STEPS; ++t) {
        for (int i = tid; i < NSYN * N_NEURONS; i += 1024) inpi[i] = 0;
        __syncthreads();
        // external input for step t (exclusive per neuron, non-atomic)
        for (int n = tid; n < N_NEURONS; n += 1024) {
            int q0 = 0, q1 = 0, q2 = 0, q3 = 0, q4 = 0;
            int e1 = rp[n + 1];
            for (int e = rp[n]; e < e1; ++e) {
                unsigned b = bits[psrc[e]];
                if ((b >> t) & 1u) {
                    const float4* P = (const float4*)(pay + 8 * (size_t)e);
                    float4 pa = P[0]; float4 pb = P[1];
                    float w = pa.x;
                    q0 += __float2int_rn(w * pa.y * SCALE_F);
                    q1 += __float2int_rn(w * pa.z * SCALE_F);
                    q2 += __float2int_rn(w * pa.w * SCALE_F);
                    q3 += __float2int_rn(w * pb.x * SCALE_F);
                    q4 += __float2int_rn(w * pb.y * SCALE_F);
                }
            }
            inpi[n * NSYN + 0] = q0; inpi[n * NSYN + 1] = q1; inpi[n * NSYN + 2] = q2;
            inpi[n * NSYN + 3] = q3; inpi[n * NSYN + 4] = q4;
        }
        __syncthreads();
        // recurrent scatter (int atomics: exact, order-invariant)
        if (t > 0) {
            for (int e = tid; e < E_REC; e += 1024) {
                int2 pcol = ((const int2*)rec_idx)[e];
                int post = pcol.x, col = pcol.y;
                int d1 = col / N_NEURONS;
                int pre = col - d1 * N_NEURONS;
                int st = t - 1 - d1;
                if (st < 0) continue;
                if (zbuf[(st % MAX_DELAY) * N_NEURONS + pre] != 0.0f) {
                    float w = rec_w[e];
                    atomicAdd(&inpi[post * NSYN + 0], __float2int_rn(w * rec_fac[5 * e + 0] * SCALE_F));
                    atomicAdd(&inpi[post * NSYN + 1], __float2int_rn(w * rec_fac[5 * e + 1] * SCALE_F));
                    atomicAdd(&inpi[post * NSYN + 2], __float2int_rn(w * rec_fac[5 * e + 2] * SCALE_F));
                    atomicAdd(&inpi[post * NSYN + 3], __float2int_rn(w * rec_fac[5 * e + 3] * SCALE_F));
                    atomicAdd(&inpi[post * NSYN + 4], __float2int_rn(w * rec_fac[5 * e + 4] * SCALE_F));
                }
            }
        }
        __syncthreads();
        // neuron update
        for (int n = tid; n < N_NEURONS; n += 1024) {
            float pz = (t == 0) ? 0.f : zbuf[((t - 1) % MAX_DELAY) * N_NEURONS + n];
            float prx[NSYN], pcx[NSYN];
            float ic = 0.f;
#pragma unroll
            for (int s = 0; s < NSYN; ++s) {
                prx[s] = pra[n * NSYN + s];
                pcx[s] = pca[n * NSYN + s];
                ic += pcx[s];
            }
            float a0 = asc[2 * n], a1 = asc[2 * n + 1];
            float c1 = ic + a0 + a1 + gg[n];
            float dv = decay[n] * vv[n] + cf[n] * c1;
            float nv = (pz > 0.5f) ? vres[n] : dv;
            float tr = tref[n];
            float nr = rr[n] + pz * tr - DT;
            nr = fminf(fmaxf(nr, 0.0f), tr);
            asc[2 * n]     = expf(-DT * kk[2 * n])     * a0 + pz * aamps[2 * n];
            asc[2 * n + 1] = expf(-DT * kk[2 * n + 1]) * a1 + pz * aamps[2 * n + 1];
#pragma unroll
            for (int s = 0; s < NSYN; ++s) {
                float is = (float)((double)inpi[n * NSYN + s] * INV_SCALE);
                float sd = sdec[s];
                float np = pcx[s] * sd + DT * sd * prx[s];
                pra[n * NSYN + s] = prx[s] * sd + is * psci[s];
                pca[n * NSYN + s] = np;
            }
            vv[n] = nv; rr[n] = nr;
            float vsc = (nv - vth[n]) / norm[n];
            float z = (vsc > 0.0f) ? 1.0f : 0.0f;
            float nz = (nr > 0.0f) ? 0.0f : z;
            zbuf[(t % MAX_DELAY) * N_NEURONS + n] = nz;
            out[(size_t)t * N_NEURONS + n] = nz;
        }
        __syncthreads();
    }
}

extern "C" void kernel_launch(void* const* d_in, const int* in_sizes, int n_in,
                              void* d_out, int out_size, void* d_ws, size_t ws_size,
                              hipStream_t stream) {
    const float* lgn_spikes  = (const float*)d_in[0];
    const float* bkg_spikes  = (const float*)d_in[1];
    const int*   rec_indices = (const int*)  d_in[2];
    const float* rec_w       = (const float*)d_in[3];
    const float* rec_factors = (const float*)d_in[4];
    const int*   lgn_indices = (const int*)  d_in[5];
    const float* lgn_w       = (const float*)d_in[6];
    const float* lgn_factors = (const float*)d_in[7];
    const int*   bkg_indices = (const int*)  d_in[8];
    const float* bkg_w       = (const float*)d_in[9];
    const float* bkg_factors = (const float*)d_in[10];
    const float* decay       = (const float*)d_in[11];
    const float* current_factor = (const float*)d_in[12];
    const float* v_reset     = (const float*)d_in[13];
    const float* t_ref       = (const float*)d_in[14];
    const float* k           = (const float*)d_in[15];
    const float* asc_amps    = (const float*)d_in[16];
    const float* v_th        = (const float*)d_in[17];
    const float* normalizer  = (const float*)d_in[18];
    const float* gathered_g  = (const float*)d_in[19];
    const float* syn_decay   = (const float*)d_in[20];
    const float* psc_initial = (const float*)d_in[21];

    float* ws = (float*)d_ws;
    int*      flag = (int*)(ws + OFF_FLAG);
    int*      cnt  = (int*)(ws + OFF_CNT);
    int*      rp   = (int*)(ws + OFF_RP);
    int*      cur  = (int*)(ws + OFF_CUR);
    int*      bsum = (int*)(ws + OFF_BSUM);
    unsigned* bits = (unsigned*)(ws + OFF_BITS);
    int*      psrc = (int*)(ws + OFF_PSRC);
    float*    pay  = ws + OFF_PAY;
    float*    zbuf = ws + OFF_ZBUF;
    float*    vv   = ws + OFF_V;
    float*    rr   = ws + OFF_R;
    float*    asc  = ws + OFF_ASC;
    float*    pra  = ws + OFF_PR;
    float*    pca  = ws + OFF_PC;
    int*      inpi = (int*)(ws + OFF_INPI);
    float*    out  = (float*)d_out;

    zero_small<<<(100032 + 1023) / 1024, 1024, 0, stream>>>(flag, 100032);
    spk_bits_k<<<(N_SRC + 255) / 256, 256, 0, stream>>>(lgn_spikes, bkg_spikes, bits);
    csr_count<<<(E_EXT + 255) / 256, 256, 0, stream>>>(lgn_indices, bkg_indices, cnt);
    scanA<<<NBLK_N, 256, 0, stream>>>(cnt, rp, bsum);
    scanB<<<1, 512, 0, stream>>>(bsum);
    scanC<<<NBLK_N, 256, 0, stream>>>(rp, cur, bsum);
    csr_fill<<<(E_EXT + 255) / 256, 256, 0, stream>>>(
        lgn_indices, lgn_w, lgn_factors, bkg_indices, bkg_w, bkg_factors,
        cur, psrc, pay);
    fused_scan<<<NBLK_N, 256, 0, stream>>>(
        rp, psrc, pay, bits,
        decay, current_factor, v_reset, t_ref, k, asc_amps,
        v_th, normalizer, gathered_g, syn_decay, psc_initial,
        out, flag);
    fallback_redo<<<1, 1024, 0, stream>>>(
        rp, psrc, pay, bits, rec_indices, rec_w, rec_factors,
        decay, current_factor, v_reset, t_ref, k, asc_amps,
        v_th, normalizer, gathered_g, syn_decay, psc_initial,
        zbuf, vv, rr, asc, pra, pca, inpi, out, flag);
}

// Round 5
// 114.044 us; speedup vs baseline: 3.5468x; 1.1507x over previous
//
#include <hip/hip_runtime.h>

#define N_NEURONS 100000
#define MAX_DELAY 5
#define NSYN 5
#define T_STEPS 20
#define N_LGN 17400
#define N_BKG 100
#define N_SRC (N_LGN + N_BKG)        // 17500
#define E_REC 2000000
#define E_LGN 600000
#define E_BKG 200000
#define E_EXT (E_LGN + E_BKG)        // 800000
#define DT 1.0f
#define NBLK_N 391                   // ceil(N/256)
#define SCALE_F 16777216.0f          // 2^24 fixed-point (order-invariant accumulation)
#define INV_SCALE (1.0 / 16777216.0)

// ---------------- ws layout (4-byte units) ----------------
#define OFF_FLAG  0u                 // int[32]     : [0]=any-spike flag
#define OFF_CNT   32u                // int[N]      : per-post edge counts (zeroed with flag)
#define OFF_RP    100032u            // int[N+1]+pad: CSR row pointers
#define OFF_BSUM  200048u            // int[512]    : scan block sums
#define OFF_BITS  200560u            // uint[N_SRC] : 20-bit spike masks
#define OFF_RANK  218064u            // int[E_EXT]  : rank of edge within its post (coalesced)
#define OFF_PERM  1018064u           // int[E_EXT]  : CSR slot -> edge id
#define OFF_ZBUF  1818064u           // float[5N]   (fallback only)
#define OFF_V     2318064u           // float[N]
#define OFF_R     2418064u
#define OFF_ASC   2518064u           // float[2N]
#define OFF_PR    2718064u           // float[5N]
#define OFF_PC    3218064u           // float[5N]
#define OFF_INPI  3718064u           // int[5N]
// total ~4.2M units = ~17 MB (ws >= 72 MB proven in round 3)

// Fused: zero {flag,cnt} + build 20-bit spike masks.
__global__ void prep(const float* __restrict__ lgn, const float* __restrict__ bkg,
                     unsigned* __restrict__ bits, int* __restrict__ zp) {
    int tid = blockIdx.x * blockDim.x + threadIdx.x;
    if (tid < 100032) zp[tid] = 0;
    int i = tid - 100032;
    if (i < 0 || i >= N_SRC) return;
    unsigned b = 0;
    if (i < N_LGN) {
#pragma unroll
        for (int t = 0; t < T_STEPS; ++t)
            if (lgn[t * N_LGN + i] != 0.0f) b |= (1u << t);
    } else {
        int j = i - N_LGN;
#pragma unroll
        for (int t = 0; t < T_STEPS; ++t)
            if (bkg[t * N_BKG + j] != 0.0f) b |= (1u << t);
    }
    bits[i] = b;
}

// One atomic pass: count AND coalesced rank store.
__global__ void count_rank(const int* __restrict__ lgn_idx, const int* __restrict__ bkg_idx,
                           int* __restrict__ cnt, int* __restrict__ rank) {
    int e = blockIdx.x * blockDim.x + threadIdx.x;
    if (e >= E_EXT) return;
    int post = (e < E_LGN) ? lgn_idx[2 * e] : bkg_idx[2 * (e - E_LGN)];
    rank[e] = atomicAdd(&cnt[post], 1);
}

__global__ void scanA(const int* __restrict__ cnt, int* __restrict__ rp, int* __restrict__ bsum) {
    __shared__ int sh[256];
    int i = blockIdx.x * 256 + threadIdx.x;
    int v = (i < N_NEURONS) ? cnt[i] : 0;
    sh[threadIdx.x] = v;
    __syncthreads();
    for (int off = 1; off < 256; off <<= 1) {
        int t = (threadIdx.x >= off) ? sh[threadIdx.x - off] : 0;
        __syncthreads();
        sh[threadIdx.x] += t;
        __syncthreads();
    }
    if (i < N_NEURONS) rp[i] = sh[threadIdx.x] - v;   // exclusive within block
    if (threadIdx.x == 255) bsum[blockIdx.x] = sh[255];
}

// Fused scanB+scanC: every block redundantly scans the 391 block sums in LDS,
// then adds its own exclusive offset to its 256 neurons' row pointers.
__global__ void scanBC(int* __restrict__ rp, const int* __restrict__ bsum) {
    __shared__ int sh[512];
    __shared__ int excl[512];
    int v = (threadIdx.x < NBLK_N) ? bsum[threadIdx.x] : 0;
    sh[threadIdx.x] = v;
    __syncthreads();
    for (int off = 1; off < 512; off <<= 1) {
        int t = (threadIdx.x >= off) ? sh[threadIdx.x - off] : 0;
        __syncthreads();
        sh[threadIdx.x] += t;
        __syncthreads();
    }
    excl[threadIdx.x] = sh[threadIdx.x] - v;
    __syncthreads();
    int off0 = excl[blockIdx.x];
    if (threadIdx.x < 256) {
        int i = blockIdx.x * 256 + threadIdx.x;
        if (i < N_NEURONS) rp[i] += off0;
    }
    if (blockIdx.x == 0 && threadIdx.x == 0) rp[N_NEURONS] = E_EXT;
}

// Minimum scatter: 4B permutation entry per edge (payload stays in place).
__global__ void perm_scatter(const int* __restrict__ lgn_idx, const int* __restrict__ bkg_idx,
                             const int* __restrict__ rp, const int* __restrict__ rank,
                             int* __restrict__ perm) {
    int e = blockIdx.x * blockDim.x + threadIdx.x;
    if (e >= E_EXT) return;
    int post = (e < E_LGN) ? lgn_idx[2 * e] : bkg_idx[2 * (e - E_LGN)];
    perm[rp[post] + rank[e]] = e;
}

// Fused: per-neuron external-input gather (perm-indirect payload reads,
// int32 fixed-point -> order-invariant/deterministic) + 20-step GLIF scan
// in registers, assuming zero recurrent input. If any spike fires anywhere,
// raise flag; fallback_redo recomputes exactly.
__global__ void __launch_bounds__(256) fused_scan(
    const int* __restrict__ rp, const int* __restrict__ perm,
    const unsigned* __restrict__ bits,
    const int* __restrict__ lgn_idx, const float* __restrict__ lgn_w,
    const float* __restrict__ lgn_fac,
    const int* __restrict__ bkg_idx, const float* __restrict__ bkg_w,
    const float* __restrict__ bkg_fac,
    const float* __restrict__ decay, const float* __restrict__ cf,
    const float* __restrict__ vres, const float* __restrict__ tref,
    const float* __restrict__ kk, const float* __restrict__ aamps,
    const float* __restrict__ vth, const float* __restrict__ norm,
    const float* __restrict__ gg, const float* __restrict__ sdec,
    const float* __restrict__ psci,
    float* __restrict__ out, int* __restrict__ flag)
{
    int n = blockIdx.x * 256 + threadIdx.x;
    if (n >= N_NEURONS) return;

    int acc[T_STEPS][NSYN] = {};
    int e1 = rp[n + 1];
    for (int e = rp[n]; e < e1; ++e) {
        int pe = perm[e];
        int srow;
        if (pe < E_LGN) {
            srow = lgn_idx[2 * pe + 1];
        } else {
            srow = N_LGN + bkg_idx[2 * (pe - E_LGN) + 1];
        }
        unsigned b = bits[srow];
        if (!b) continue;                       // source never fires: skip payload
        float w, f0, f1, f2, f3, f4;
        if (pe < E_LGN) {
            w = lgn_w[pe];
            const float* f = lgn_fac + 5 * (size_t)pe;
            f0 = f[0]; f1 = f[1]; f2 = f[2]; f3 = f[3]; f4 = f[4];
        } else {
            int bb = pe - E_LGN;
            w = bkg_w[bb];
            const float* f = bkg_fac + 5 * (size_t)bb;
            f0 = f[0]; f1 = f[1]; f2 = f[2]; f3 = f[3]; f4 = f[4];
        }
        int q0 = __float2int_rn(w * f0 * SCALE_F);
        int q1 = __float2int_rn(w * f1 * SCALE_F);
        int q2 = __float2int_rn(w * f2 * SCALE_F);
        int q3 = __float2int_rn(w * f3 * SCALE_F);
        int q4 = __float2int_rn(w * f4 * SCALE_F);
#pragma unroll
        for (int t = 0; t < T_STEPS; ++t) {
            if ((b >> t) & 1u) {
                acc[t][0] += q0; acc[t][1] += q1; acc[t][2] += q2;
                acc[t][3] += q3; acc[t][4] += q4;
            }
        }
    }

    float dec = decay[n], cfa = cf[n], vr = vres[n], tr = tref[n];
    float ek0 = expf(-DT * kk[2 * n]), ek1 = expf(-DT * kk[2 * n + 1]);
    float aa0 = aamps[2 * n], aa1 = aamps[2 * n + 1];
    float vt = vth[n], nm = norm[n], g = gg[n];
    float sd0 = sdec[0], sd1 = sdec[1], sd2 = sdec[2], sd3 = sdec[3], sd4 = sdec[4];
    float pi0 = psci[0], pi1 = psci[1], pi2 = psci[2], pi3 = psci[3], pi4 = psci[4];

    float pr0 = 0.f, pr1 = 0.f, pr2 = 0.f, pr3 = 0.f, pr4 = 0.f;
    float pc0 = 0.f, pc1 = 0.f, pc2 = 0.f, pc3 = 0.f, pc4 = 0.f;
    float v = 0.f, r = 0.f, a0 = 0.f, a1 = 0.f, pz = 0.f;
    bool anyf = false;

#pragma unroll
    for (int t = 0; t < T_STEPS; ++t) {
        float ic = pc0 + pc1 + pc2 + pc3 + pc4;      // input_current uses OLD psc
        float c1 = ic + a0 + a1 + g;
        float dv = dec * v + cfa * c1;
        float nv = (pz > 0.5f) ? vr : dv;
        float nr = r + pz * tr - DT;
        nr = fminf(fmaxf(nr, 0.0f), tr);
        a0 = ek0 * a0 + pz * aa0;
        a1 = ek1 * a1 + pz * aa1;

        float i0 = (float)((double)acc[t][0] * INV_SCALE);
        float i1 = (float)((double)acc[t][1] * INV_SCALE);
        float i2 = (float)((double)acc[t][2] * INV_SCALE);
        float i3 = (float)((double)acc[t][3] * INV_SCALE);
        float i4 = (float)((double)acc[t][4] * INV_SCALE);

        float np0 = pc0 * sd0 + DT * sd0 * pr0;      // new psc from OLD psc_rise
        float np1 = pc1 * sd1 + DT * sd1 * pr1;
        float np2 = pc2 * sd2 + DT * sd2 * pr2;
        float np3 = pc3 * sd3 + DT * sd3 * pr3;
        float np4 = pc4 * sd4 + DT * sd4 * pr4;
        pr0 = pr0 * sd0 + i0 * pi0;  pc0 = np0;
        pr1 = pr1 * sd1 + i1 * pi1;  pc1 = np1;
        pr2 = pr2 * sd2 + i2 * pi2;  pc2 = np2;
        pr3 = pr3 * sd3 + i3 * pi3;  pc3 = np3;
        pr4 = pr4 * sd4 + i4 * pi4;  pc4 = np4;

        v = nv; r = nr;
        float vsc = (nv - vt) / nm;
        float z = (vsc > 0.0f) ? 1.0f : 0.0f;
        float nz = (nr > 0.0f) ? 0.0f : z;
        out[(size_t)t * N_NEURONS + n] = nz;
        pz = nz;
        anyf = anyf || (nz != 0.0f);
    }
    if (anyf) atomicAdd(flag, 1);
}

// Exact coupled redo inside ONE workgroup (grid sync == __syncthreads()).
// Runs only if fused_scan detected any spike; early-exits (~2us) otherwise.
__global__ void __launch_bounds__(1024) fallback_redo(
    const int* __restrict__ rp, const int* __restrict__ perm,
    const unsigned* __restrict__ bits,
    const int* __restrict__ lgn_idx, const float* __restrict__ lgn_w,
    const float* __restrict__ lgn_fac,
    const int* __restrict__ bkg_idx, const float* __restrict__ bkg_w,
    const float* __restrict__ bkg_fac,
    const int* __restrict__ rec_idx, const float* __restrict__ rec_w,
    const float* __restrict__ rec_fac,
    const float* __restrict__ decay, const float* __restrict__ cf,
    const float* __restrict__ vres, const float* __restrict__ tref,
    const float* __restrict__ kk, const float* __restrict__ aamps,
    const float* __restrict__ vth, const float* __restrict__ norm,
    const float* __restrict__ gg, const float* __restrict__ sdec,
    const float* __restrict__ psci,
    float* __restrict__ zbuf, float* __restrict__ vv, float* __restrict__ rr,
    float* __restrict__ asc, float* __restrict__ pra, float* __restrict__ pca,
    int* __restrict__ inpi, float* __restrict__ out, const int* __restrict__ flag)
{
    if (flag[0] == 0) return;
    int tid = threadIdx.x;
    for (int i = tid; i < N_NEURONS; i += 1024) { vv[i] = 0.f; rr[i] = 0.f; }
    for (int i = tid; i < 2 * N_NEURONS; i += 1024) asc[i] = 0.f;
    for (int i = tid; i < NSYN * N_NEURONS; i += 1024) { pra[i] = 0.f; pca[i] = 0.f; }
    for (int i = tid; i < MAX_DELAY * N_NEURONS; i += 1024) zbuf[i] = 0.f;
    __syncthreads();

    for (int t = 0; t < T_STEPS; ++t) {
        for (int i = tid; i < NSYN * N_NEURONS; i += 1024) inpi[i] = 0;
        __syncthreads();
        // external input for step t (exclusive per neuron, non-atomic)
        for (int n = tid; n < N_NEURONS; n += 1024) {
            int q0 = 0, q1 = 0, q2 = 0, q3 = 0, q4 = 0;
            int e1 = rp[n + 1];
            for (int e = rp[n]; e < e1; ++e) {
                int pe = perm[e];
                int srow; float w; const float* f;
                if (pe < E_LGN) {
                    srow = lgn_idx[2 * pe + 1];
                    w = lgn_w[pe]; f = lgn_fac + 5 * (size_t)pe;
                } else {
                    int bb = pe - E_LGN;
                    srow = N_LGN + bkg_idx[2 * bb + 1];
                    w = bkg_w[bb]; f = bkg_fac + 5 * (size_t)bb;
                }
                if ((bits[srow] >> t) & 1u) {
                    q0 += __float2int_rn(w * f[0] * SCALE_F);
                    q1 += __float2int_rn(w * f[1] * SCALE_F);
                    q2 += __float2int_rn(w * f[2] * SCALE_F);
                    q3 += __float2int_rn(w * f[3] * SCALE_F);
                    q4 += __float2int_rn(w * f[4] * SCALE_F);
                }
            }
            inpi[n * NSYN + 0] = q0; inpi[n * NSYN + 1] = q1; inpi[n * NSYN + 2] = q2;
            inpi[n * NSYN + 3] = q3; inpi[n * NSYN + 4] = q4;
        }
        __syncthreads();
        // recurrent scatter (int atomics: exact, order-invariant)
        if (t > 0) {
            for (int e = tid; e < E_REC; e += 1024) {
                int2 pcol = ((const int2*)rec_idx)[e];
                int post = pcol.x, col = pcol.y;
                int d1 = col / N_NEURONS;
                int pre = col - d1 * N_NEURONS;
                int st = t - 1 - d1;
                if (st < 0) continue;
                if (zbuf[(st % MAX_DELAY) * N_NEURONS + pre] != 0.0f) {
                    float w = rec_w[e];
                    atomicAdd(&inpi[post * NSYN + 0], __float2int_rn(w * rec_fac[5 * e + 0] * SCALE_F));
                    atomicAdd(&inpi[post * NSYN + 1], __float2int_rn(w * rec_fac[5 * e + 1] * SCALE_F));
                    atomicAdd(&inpi[post * NSYN + 2], __float2int_rn(w * rec_fac[5 * e + 2] * SCALE_F));
                    atomicAdd(&inpi[post * NSYN + 3], __float2int_rn(w * rec_fac[5 * e + 3] * SCALE_F));
                    atomicAdd(&inpi[post * NSYN + 4], __float2int_rn(w * rec_fac[5 * e + 4] * SCALE_F));
                }
            }
        }
        __syncthreads();
        // neuron update
        for (int n = tid; n < N_NEURONS; n += 1024) {
            float pz = (t == 0) ? 0.f : zbuf[((t - 1) % MAX_DELAY) * N_NEURONS + n];
            float prx[NSYN], pcx[NSYN];
            float ic = 0.f;
#pragma unroll
            for (int s = 0; s < NSYN; ++s) {
                prx[s] = pra[n * NSYN + s];
                pcx[s] = pca[n * NSYN + s];
                ic += pcx[s];
            }
            float a0 = asc[2 * n], a1 = asc[2 * n + 1];
            float c1 = ic + a0 + a1 + gg[n];
            float dv = decay[n] * vv[n] + cf[n] * c1;
            float nv = (pz > 0.5f) ? vres[n] : dv;
            float tr = tref[n];
            float nr = rr[n] + pz * tr - DT;
            nr = fminf(fmaxf(nr, 0.0f), tr);
            asc[2 * n]     = expf(-DT * kk[2 * n])     * a0 + pz * aamps[2 * n];
            asc[2 * n + 1] = expf(-DT * kk[2 * n + 1]) * a1 + pz * aamps[2 * n + 1];
#pragma unroll
            for (int s = 0; s < NSYN; ++s) {
                float is = (float)((double)inpi[n * NSYN + s] * INV_SCALE);
                float sd = sdec[s];
                float np = pcx[s] * sd + DT * sd * prx[s];
                pra[n * NSYN + s] = prx[s] * sd + is * psci[s];
                pca[n * NSYN + s] = np;
            }
            vv[n] = nv; rr[n] = nr;
            float vsc = (nv - vth[n]) / norm[n];
            float z = (vsc > 0.0f) ? 1.0f : 0.0f;
            float nz = (nr > 0.0f) ? 0.0f : z;
            zbuf[(t % MAX_DELAY) * N_NEURONS + n] = nz;
            out[(size_t)t * N_NEURONS + n] = nz;
        }
        __syncthreads();
    }
}

extern "C" void kernel_launch(void* const* d_in, const int* in_sizes, int n_in,
                              void* d_out, int out_size, void* d_ws, size_t ws_size,
                              hipStream_t stream) {
    const float* lgn_spikes  = (const float*)d_in[0];
    const float* bkg_spikes  = (const float*)d_in[1];
    const int*   rec_indices = (const int*)  d_in[2];
    const float* rec_w       = (const float*)d_in[3];
    const float* rec_factors = (const float*)d_in[4];
    const int*   lgn_indices = (const int*)  d_in[5];
    const float* lgn_w       = (const float*)d_in[6];
    const float* lgn_factors = (const float*)d_in[7];
    const int*   bkg_indices = (const int*)  d_in[8];
    const float* bkg_w       = (const float*)d_in[9];
    const float* bkg_factors = (const float*)d_in[10];
    const float* decay       = (const float*)d_in[11];
    const float* current_factor = (const float*)d_in[12];
    const float* v_reset     = (const float*)d_in[13];
    const float* t_ref       = (const float*)d_in[14];
    const float* k           = (const float*)d_in[15];
    const float* asc_amps    = (const float*)d_in[16];
    const float* v_th        = (const float*)d_in[17];
    const float* normalizer  = (const float*)d_in[18];
    const float* gathered_g  = (const float*)d_in[19];
    const float* syn_decay   = (const float*)d_in[20];
    const float* psc_initial = (const float*)d_in[21];

    float* ws = (float*)d_ws;
    int*      flag = (int*)(ws + OFF_FLAG);
    int*      rp   = (int*)(ws + OFF_RP);
    int*      bsum = (int*)(ws + OFF_BSUM);
    unsigned* bits = (unsigned*)(ws + OFF_BITS);
    int*      rank = (int*)(ws + OFF_RANK);
    int*      perm = (int*)(ws + OFF_PERM);
    int*      cnt  = (int*)(ws + OFF_CNT);
    float*    zbuf = ws + OFF_ZBUF;
    float*    vv   = ws + OFF_V;
    float*    rr   = ws + OFF_R;
    float*    asc  = ws + OFF_ASC;
    float*    pra  = ws + OFF_PR;
    float*    pca  = ws + OFF_PC;
    int*      inpi = (int*)(ws + OFF_INPI);
    float*    out  = (float*)d_out;

    prep<<<(100032 + N_SRC + 255) / 256, 256, 0, stream>>>(lgn_spikes, bkg_spikes, bits, flag);
    count_rank<<<(E_EXT + 255) / 256, 256, 0, stream>>>(lgn_indices, bkg_indices, cnt, rank);
    scanA<<<NBLK_N, 256, 0, stream>>>(cnt, rp, bsum);
    scanBC<<<NBLK_N, 512, 0, stream>>>(rp, bsum);
    perm_scatter<<<(E_EXT + 255) / 256, 256, 0, stream>>>(lgn_indices, bkg_indices, rp, rank, perm);
    fused_scan<<<NBLK_N, 256, 0, stream>>>(
        rp, perm, bits,
        lgn_indices, lgn_w, lgn_factors, bkg_indices, bkg_w, bkg_factors,
        decay, current_factor, v_reset, t_ref, k, asc_amps,
        v_th, normalizer, gathered_g, syn_decay, psc_initial,
        out, flag);
    fallback_redo<<<1, 1024, 0, stream>>>(
        rp, perm, bits,
        lgn_indices, lgn_w, lgn_factors, bkg_indices, bkg_w, bkg_factors,
        rec_indices, rec_w, rec_factors,
        decay, current_factor, v_reset, t_ref, k, asc_amps,
        v_th, normalizer, gathered_g, syn_decay, psc_initial,
        zbuf, vv, rr, asc, pra, pca, inpi, out, flag);
}

// Round 6
// 76.656 us; speedup vs baseline: 5.2767x; 1.4877x over previous
//
#include <hip/hip_runtime.h>

#define N_NEURONS 100000
#define MAX_DELAY 5
#define NSYN 5
#define T_STEPS 20
#define N_LGN 17400
#define N_BKG 100
#define N_SRC (N_LGN + N_BKG)        // 17500
#define E_REC 2000000
#define E_LGN 600000
#define E_BKG 200000
#define E_EXT (E_LGN + E_BKG)        // 800000
#define DT 1.0f
#define NBLK_N 391                   // ceil(N/256)
#define NN_PER_BLK 64
#define NBLK_FUSED 1563              // ceil(N/64)
#define ACC_STRIDE 101               // 100 + 1 pad (bank-conflict-free scan reads)
#define SCALE_F 16777216.0f          // 2^24 fixed-point (order-invariant accumulation)
#define INV_SCALE (1.0 / 16777216.0)

// ---------------- ws layout (4-byte units) ----------------
#define OFF_FLAG  0u                 // int[32]     : [0]=any-spike flag
#define OFF_CNT   32u                // int[N]      : per-post FIRING edge counts
#define OFF_RP    100032u            // int[N+1]+pad
#define OFF_BSUM  200048u            // int[512]
#define OFF_BITS  200560u            // uint[N_SRC]
#define OFF_RANK  218064u            // int[E_EXT]
#define OFF_PERM  1018064u           // int[E_EXT] (only firing slots used)
#define OFF_PAYN  1818064u           // int[8*E_EXT]: {mask,q0..q4,post,0} per edge
#define OFF_ZBUF  8218064u           // float[5N]   (fallback only)
#define OFF_V     8718064u
#define OFF_R     8818064u
#define OFF_ASC   8918064u           // float[2N]
#define OFF_PR    9118064u           // float[5N]
#define OFF_PC    9618064u           // float[5N]
#define OFF_INPI  10118064u          // int[5N]
// ends 10,618,064 units = 42.5 MB (ws >= 72 MB proven round 3)

// Fused: zero {flag,cnt} + build 20-bit spike masks.
__global__ void prep(const float* __restrict__ lgn, const float* __restrict__ bkg,
                     unsigned* __restrict__ bits, int* __restrict__ zp) {
    int tid = blockIdx.x * blockDim.x + threadIdx.x;
    if (tid < 100032) zp[tid] = 0;
    int i = tid - 100032;
    if (i < 0 || i >= N_SRC) return;
    unsigned b = 0;
    if (i < N_LGN) {
#pragma unroll
        for (int t = 0; t < T_STEPS; ++t)
            if (lgn[t * N_LGN + i] != 0.0f) b |= (1u << t);
    } else {
        int j = i - N_LGN;
#pragma unroll
        for (int t = 0; t < T_STEPS; ++t)
            if (bkg[t * N_BKG + j] != 0.0f) b |= (1u << t);
    }
    bits[i] = b;
}

// Edge-parallel, coalesced: pre-quantized 32B record per edge + filtered count/rank.
__global__ void pack_nat(const int* __restrict__ lgn_idx, const float* __restrict__ lgn_w,
                         const float* __restrict__ lgn_fac,
                         const int* __restrict__ bkg_idx, const float* __restrict__ bkg_w,
                         const float* __restrict__ bkg_fac,
                         const unsigned* __restrict__ bits,
                         int* __restrict__ cnt, int* __restrict__ rank,
                         int* __restrict__ payn) {
    int e = blockIdx.x * blockDim.x + threadIdx.x;
    if (e >= E_EXT) return;
    int post, srow; float w; const float* f;
    if (e < E_LGN) {
        int2 pc2 = ((const int2*)lgn_idx)[e];
        post = pc2.x; srow = pc2.y;
        w = lgn_w[e]; f = lgn_fac + 5 * (size_t)e;
    } else {
        int b = e - E_LGN;
        int2 pc2 = ((const int2*)bkg_idx)[b];
        post = pc2.x; srow = N_LGN + pc2.y;
        w = bkg_w[b]; f = bkg_fac + 5 * (size_t)b;
    }
    unsigned m = bits[srow];          // random read over 70KB: L2-resident
    float wsc = w * SCALE_F;
    int4 a, b4;
    a.x = (int)m;
    a.y = __float2int_rn(wsc * f[0]);
    a.z = __float2int_rn(wsc * f[1]);
    a.w = __float2int_rn(wsc * f[2]);
    b4.x = __float2int_rn(wsc * f[3]);
    b4.y = __float2int_rn(wsc * f[4]);
    b4.z = post;
    b4.w = 0;
    int4* d = (int4*)(payn + 8 * (size_t)e);
    d[0] = a;
    d[1] = b4;
    if (m) rank[e] = atomicAdd(&cnt[post], 1);   // firing edges only
}

__global__ void scanA(const int* __restrict__ cnt, int* __restrict__ rp, int* __restrict__ bsum) {
    __shared__ int sh[256];
    int i = blockIdx.x * 256 + threadIdx.x;
    int v = (i < N_NEURONS) ? cnt[i] : 0;
    sh[threadIdx.x] = v;
    __syncthreads();
    for (int off = 1; off < 256; off <<= 1) {
        int t = (threadIdx.x >= off) ? sh[threadIdx.x - off] : 0;
        __syncthreads();
        sh[threadIdx.x] += t;
        __syncthreads();
    }
    if (i < N_NEURONS) rp[i] = sh[threadIdx.x] - v;   // exclusive within block
    if (threadIdx.x == 255) bsum[blockIdx.x] = sh[255];
}

// Fused scanB+scanC (each block redundantly scans the 391 block sums).
__global__ void scanBC(int* __restrict__ rp, const int* __restrict__ bsum) {
    __shared__ int sh[512];
    __shared__ int excl[512];
    int v = (threadIdx.x < NBLK_N) ? bsum[threadIdx.x] : 0;
    sh[threadIdx.x] = v;
    __syncthreads();
    for (int off = 1; off < 512; off <<= 1) {
        int t = (threadIdx.x >= off) ? sh[threadIdx.x - off] : 0;
        __syncthreads();
        sh[threadIdx.x] += t;
        __syncthreads();
    }
    excl[threadIdx.x] = sh[threadIdx.x] - v;
    __syncthreads();
    int off0 = excl[blockIdx.x];
    if (threadIdx.x < 256) {
        int i = blockIdx.x * 256 + threadIdx.x;
        if (i < N_NEURONS) rp[i] += off0;
    }
    if (blockIdx.x == 0 && threadIdx.x == 0) rp[N_NEURONS] = sh[511];  // total firing edges
}

// 4B scatter of the permutation (firing edges only).
__global__ void perm_scatter(const int* __restrict__ lgn_idx, const int* __restrict__ bkg_idx,
                             const unsigned* __restrict__ bits,
                             const int* __restrict__ rp, const int* __restrict__ rank,
                             int* __restrict__ perm) {
    int e = blockIdx.x * blockDim.x + threadIdx.x;
    if (e >= E_EXT) return;
    int post, srow;
    if (e < E_LGN) {
        int2 pc2 = ((const int2*)lgn_idx)[e];
        post = pc2.x; srow = pc2.y;
    } else {
        int2 pc2 = ((const int2*)bkg_idx)[e - E_LGN];
        post = pc2.x; srow = N_LGN + pc2.y;
    }
    if (bits[srow] == 0) return;
    perm[rp[post] + rank[e]] = e;
}

// Block-cooperative gather into LDS + per-neuron 20-step GLIF scan.
// 256 threads <-> 64 neurons; slots of the 64 neurons walked cooperatively
// (coalesced perm reads, one 32B record read per slot), LDS atomics into
// acc[64][101]. Order-invariant int accumulation -> replay-deterministic.
__global__ void __launch_bounds__(256) fused_scan(
    const int* __restrict__ rp, const int* __restrict__ perm,
    const int* __restrict__ payn,
    const float* __restrict__ decay, const float* __restrict__ cf,
    const float* __restrict__ vres, const float* __restrict__ tref,
    const float* __restrict__ kk, const float* __restrict__ aamps,
    const float* __restrict__ vth, const float* __restrict__ norm,
    const float* __restrict__ gg, const float* __restrict__ sdec,
    const float* __restrict__ psci,
    float* __restrict__ out, int* __restrict__ flag)
{
    __shared__ int rpL[NN_PER_BLK + 1];
    __shared__ int accs[NN_PER_BLK * ACC_STRIDE];
    int tid = threadIdx.x;
    int n0 = blockIdx.x * NN_PER_BLK;
    int nn = N_NEURONS - n0; if (nn > NN_PER_BLK) nn = NN_PER_BLK;

    for (int i = tid; i < NN_PER_BLK * ACC_STRIDE; i += 256) accs[i] = 0;
    if (tid <= nn) rpL[tid] = rp[n0 + tid];
    __syncthreads();

    int s0 = rpL[0], s1 = rpL[nn];
    for (int i = s0 + tid; i < s1; i += 256) {
        int pe = perm[i];                                   // coalesced
        const int4* P = (const int4*)(payn + 8 * (size_t)pe);
        int4 a = P[0];                                      // one random 32B record
        int4 b = P[1];
        unsigned m = (unsigned)a.x;
        // binary search: rpL[ln] <= i < rpL[ln+1]
        int lo = 0, hi = nn - 1;
        while (lo < hi) {
            int mid = (lo + hi + 1) >> 1;
            if (rpL[mid] <= i) lo = mid; else hi = mid - 1;
        }
        int* acc = &accs[lo * ACC_STRIDE];
        while (m) {
            int t = __ffs(m) - 1;
            m &= m - 1;
            atomicAdd(&acc[t * 5 + 0], a.y);
            atomicAdd(&acc[t * 5 + 1], a.z);
            atomicAdd(&acc[t * 5 + 2], a.w);
            atomicAdd(&acc[t * 5 + 3], b.x);
            atomicAdd(&acc[t * 5 + 4], b.y);
        }
    }
    __syncthreads();

    if (tid >= nn) return;
    int n = n0 + tid;
    const int* acc = &accs[tid * ACC_STRIDE];

    float dec = decay[n], cfa = cf[n], vr = vres[n], tr = tref[n];
    float ek0 = expf(-DT * kk[2 * n]), ek1 = expf(-DT * kk[2 * n + 1]);
    float aa0 = aamps[2 * n], aa1 = aamps[2 * n + 1];
    float vt = vth[n], nm = norm[n], g = gg[n];
    float sd0 = sdec[0], sd1 = sdec[1], sd2 = sdec[2], sd3 = sdec[3], sd4 = sdec[4];
    float pi0 = psci[0], pi1 = psci[1], pi2 = psci[2], pi3 = psci[3], pi4 = psci[4];

    float pr0 = 0.f, pr1 = 0.f, pr2 = 0.f, pr3 = 0.f, pr4 = 0.f;
    float pc0 = 0.f, pc1 = 0.f, pc2 = 0.f, pc3 = 0.f, pc4 = 0.f;
    float v = 0.f, r = 0.f, a0 = 0.f, a1 = 0.f, pz = 0.f;
    bool anyf = false;

#pragma unroll
    for (int t = 0; t < T_STEPS; ++t) {
        float ic = pc0 + pc1 + pc2 + pc3 + pc4;      // input_current uses OLD psc
        float c1 = ic + a0 + a1 + g;
        float dv = dec * v + cfa * c1;
        float nv = (pz > 0.5f) ? vr : dv;
        float nr = r + pz * tr - DT;
        nr = fminf(fmaxf(nr, 0.0f), tr);
        a0 = ek0 * a0 + pz * aa0;
        a1 = ek1 * a1 + pz * aa1;

        float i0 = (float)((double)acc[t * 5 + 0] * INV_SCALE);
        float i1 = (float)((double)acc[t * 5 + 1] * INV_SCALE);
        float i2 = (float)((double)acc[t * 5 + 2] * INV_SCALE);
        float i3 = (float)((double)acc[t * 5 + 3] * INV_SCALE);
        float i4 = (float)((double)acc[t * 5 + 4] * INV_SCALE);

        float np0 = pc0 * sd0 + DT * sd0 * pr0;      // new psc from OLD psc_rise
        float np1 = pc1 * sd1 + DT * sd1 * pr1;
        float np2 = pc2 * sd2 + DT * sd2 * pr2;
        float np3 = pc3 * sd3 + DT * sd3 * pr3;
        float np4 = pc4 * sd4 + DT * sd4 * pr4;
        pr0 = pr0 * sd0 + i0 * pi0;  pc0 = np0;
        pr1 = pr1 * sd1 + i1 * pi1;  pc1 = np1;
        pr2 = pr2 * sd2 + i2 * pi2;  pc2 = np2;
        pr3 = pr3 * sd3 + i3 * pi3;  pc3 = np3;
        pr4 = pr4 * sd4 + i4 * pi4;  pc4 = np4;

        v = nv; r = nr;
        float vsc = (nv - vt) / nm;
        float z = (vsc > 0.0f) ? 1.0f : 0.0f;
        float nz = (nr > 0.0f) ? 0.0f : z;
        out[(size_t)t * N_NEURONS + n] = nz;
        pz = nz;
        anyf = anyf || (nz != 0.0f);
    }
    if (anyf) atomicAdd(flag, 1);
}

// Exact coupled redo inside ONE workgroup; early-exits if no spike detected.
__global__ void __launch_bounds__(1024) fallback_redo(
    const int* __restrict__ rp, const int* __restrict__ perm,
    const int* __restrict__ payn,
    const int* __restrict__ rec_idx, const float* __restrict__ rec_w,
    const float* __restrict__ rec_fac,
    const float* __restrict__ decay, const float* __restrict__ cf,
    const float* __restrict__ vres, const float* __restrict__ tref,
    const float* __restrict__ kk, const float* __restrict__ aamps,
    const float* __restrict__ vth, const float* __restrict__ norm,
    const float* __restrict__ gg, const float* __restrict__ sdec,
    const float* __restrict__ psci,
    float* __restrict__ zbuf, float* __restrict__ vv, float* __restrict__ rr,
    float* __restrict__ asc, float* __restrict__ pra, float* __restrict__ pca,
    int* __restrict__ inpi, float* __restrict__ out, const int* __restrict__ flag)
{
    if (flag[0] == 0) return;
    int tid = threadIdx.x;
    for (int i = tid; i < N_NEURONS; i += 1024) { vv[i] = 0.f; rr[i] = 0.f; }
    for (int i = tid; i < 2 * N_NEURONS; i += 1024) asc[i] = 0.f;
    for (int i = tid; i < NSYN * N_NEURONS; i += 1024) { pra[i] = 0.f; pca[i] = 0.f; }
    for (int i = tid; i < MAX_DELAY * N_NEURONS; i += 1024) zbuf[i] = 0.f;
    __syncthreads();

    for (int t = 0; t < T_STEPS; ++t) {
        for (int i = tid; i < NSYN * N_NEURONS; i += 1024) inpi[i] = 0;
        __syncthreads();
        for (int n = tid; n < N_NEURONS; n += 1024) {
            int q0 = 0, q1 = 0, q2 = 0, q3 = 0, q4 = 0;
            int e1 = rp[n + 1];
            for (int e = rp[n]; e < e1; ++e) {
                int pe = perm[e];
                const int4* P = (const int4*)(payn + 8 * (size_t)pe);
                int4 a = P[0]; int4 b = P[1];
                if (((unsigned)a.x >> t) & 1u) {
                    q0 += a.y; q1 += a.z; q2 += a.w; q3 += b.x; q4 += b.y;
                }
            }
            inpi[n * NSYN + 0] = q0; inpi[n * NSYN + 1] = q1; inpi[n * NSYN + 2] = q2;
            inpi[n * NSYN + 3] = q3; inpi[n * NSYN + 4] = q4;
        }
        __syncthreads();
        if (t > 0) {
            for (int e = tid; e < E_REC; e += 1024) {
                int2 pcol = ((const int2*)rec_idx)[e];
                int post = pcol.x, col = pcol.y;
                int d1 = col / N_NEURONS;
                int pre = col - d1 * N_NEURONS;
                int st = t - 1 - d1;
                if (st < 0) continue;
                if (zbuf[(st % MAX_DELAY) * N_NEURONS + pre] != 0.0f) {
                    float w = rec_w[e];
                    atomicAdd(&inpi[post * NSYN + 0], __float2int_rn(w * rec_fac[5 * e + 0] * SCALE_F));
                    atomicAdd(&inpi[post * NSYN + 1], __float2int_rn(w * rec_fac[5 * e + 1] * SCALE_F));
                    atomicAdd(&inpi[post * NSYN + 2], __float2int_rn(w * rec_fac[5 * e + 2] * SCALE_F));
                    atomicAdd(&inpi[post * NSYN + 3], __float2int_rn(w * rec_fac[5 * e + 3] * SCALE_F));
                    atomicAdd(&inpi[post * NSYN + 4], __float2int_rn(w * rec_fac[5 * e + 4] * SCALE_F));
                }
            }
        }
        __syncthreads();
        for (int n = tid; n < N_NEURONS; n += 1024) {
            float pz = (t == 0) ? 0.f : zbuf[((t - 1) % MAX_DELAY) * N_NEURONS + n];
            float prx[NSYN], pcx[NSYN];
            float ic = 0.f;
#pragma unroll
            for (int s = 0; s < NSYN; ++s) {
                prx[s] = pra[n * NSYN + s];
                pcx[s] = pca[n * NSYN + s];
                ic += pcx[s];
            }
            float a0 = asc[2 * n], a1 = asc[2 * n + 1];
            float c1 = ic + a0 + a1 + gg[n];
            float dv = decay[n] * vv[n] + cf[n] * c1;
            float nv = (pz > 0.5f) ? vres[n] : dv;
            float tr = tref[n];
            float nr = rr[n] + pz * tr - DT;
            nr = fminf(fmaxf(nr, 0.0f), tr);
            asc[2 * n]     = expf(-DT * kk[2 * n])     * a0 + pz * aamps[2 * n];
            asc[2 * n + 1] = expf(-DT * kk[2 * n + 1]) * a1 + pz * aamps[2 * n + 1];
#pragma unroll
            for (int s = 0; s < NSYN; ++s) {
                float is = (float)((double)inpi[n * NSYN + s] * INV_SCALE);
                float sd = sdec[s];
                float np = pcx[s] * sd + DT * sd * prx[s];
                pra[n * NSYN + s] = prx[s] * sd + is * psci[s];
                pca[n * NSYN + s] = np;
            }
            vv[n] = nv; rr[n] = nr;
            float vsc = (nv - vth[n]) / norm[n];
            float z = (vsc > 0.0f) ? 1.0f : 0.0f;
            float nz = (nr > 0.0f) ? 0.0f : z;
            zbuf[(t % MAX_DELAY) * N_NEURONS + n] = nz;
            out[(size_t)t * N_NEURONS + n] = nz;
        }
        __syncthreads();
    }
}

extern "C" void kernel_launch(void* const* d_in, const int* in_sizes, int n_in,
                              void* d_out, int out_size, void* d_ws, size_t ws_size,
                              hipStream_t stream) {
    const float* lgn_spikes  = (const float*)d_in[0];
    const float* bkg_spikes  = (const float*)d_in[1];
    const int*   rec_indices = (const int*)  d_in[2];
    const float* rec_w       = (const float*)d_in[3];
    const float* rec_factors = (const float*)d_in[4];
    const int*   lgn_indices = (const int*)  d_in[5];
    const float* lgn_w       = (const float*)d_in[6];
    const float* lgn_factors = (const float*)d_in[7];
    const int*   bkg_indices = (const int*)  d_in[8];
    const float* bkg_w       = (const float*)d_in[9];
    const float* bkg_factors = (const float*)d_in[10];
    const float* decay       = (const float*)d_in[11];
    const float* current_factor = (const float*)d_in[12];
    const float* v_reset     = (const float*)d_in[13];
    const float* t_ref       = (const float*)d_in[14];
    const float* k           = (const float*)d_in[15];
    const float* asc_amps    = (const float*)d_in[16];
    const float* v_th        = (const float*)d_in[17];
    const float* normalizer  = (const float*)d_in[18];
    const float* gathered_g  = (const float*)d_in[19];
    const float* syn_decay   = (const float*)d_in[20];
    const float* psc_initial = (const float*)d_in[21];

    float* ws = (float*)d_ws;
    int*      flag = (int*)(ws + OFF_FLAG);
    int*      cnt  = (int*)(ws + OFF_CNT);
    int*      rp   = (int*)(ws + OFF_RP);
    int*      bsum = (int*)(ws + OFF_BSUM);
    unsigned* bits = (unsigned*)(ws + OFF_BITS);
    int*      rank = (int*)(ws + OFF_RANK);
    int*      perm = (int*)(ws + OFF_PERM);
    int*      payn = (int*)(ws + OFF_PAYN);
    float*    zbuf = ws + OFF_ZBUF;
    float*    vv   = ws + OFF_V;
    float*    rr   = ws + OFF_R;
    float*    asc  = ws + OFF_ASC;
    float*    pra  = ws + OFF_PR;
    float*    pca  = ws + OFF_PC;
    int*      inpi = (int*)(ws + OFF_INPI);
    float*    out  = (float*)d_out;

    prep<<<(100032 + N_SRC + 255) / 256, 256, 0, stream>>>(lgn_spikes, bkg_spikes, bits, flag);
    pack_nat<<<(E_EXT + 255) / 256, 256, 0, stream>>>(
        lgn_indices, lgn_w, lgn_factors, bkg_indices, bkg_w, bkg_factors,
        bits, cnt, rank, payn);
    scanA<<<NBLK_N, 256, 0, stream>>>(cnt, rp, bsum);
    scanBC<<<NBLK_N, 512, 0, stream>>>(rp, bsum);
    perm_scatter<<<(E_EXT + 255) / 256, 256, 0, stream>>>(
        lgn_indices, bkg_indices, bits, rp, rank, perm);
    fused_scan<<<NBLK_FUSED, 256, 0, stream>>>(
        rp, perm, payn,
        decay, current_factor, v_reset, t_ref, k, asc_amps,
        v_th, normalizer, gathered_g, syn_decay, psc_initial,
        out, flag);
    fallback_redo<<<1, 1024, 0, stream>>>(
        rp, perm, payn, rec_indices, rec_w, rec_factors,
        decay, current_factor, v_reset, t_ref, k, asc_amps,
        v_th, normalizer, gathered_g, syn_decay, psc_initial,
        zbuf, vv, rr, asc, pra, pca, inpi, out, flag);
}

// Round 7
// 68.166 us; speedup vs baseline: 5.9339x; 1.1246x over previous
//
#include <hip/hip_runtime.h>

#define N_NEURONS 100000
#define MAX_DELAY 5
#define NSYN 5
#define T_STEPS 20
#define N_LGN 17400
#define N_BKG 100
#define N_SRC (N_LGN + N_BKG)        // 17500
#define E_REC 2000000
#define E_LGN 600000
#define E_BKG 200000
#define E_EXT (E_LGN + E_BKG)        // 800000
#define DT 1.0f
#define NN_PER_BLK 64
#define NBLK_FUSED 1563              // ceil(N/64)
#define ACC_STRIDE 101               // 100 + 1 pad
#define BW 32                        // bucket width (firing edges/post ~Poisson(5.5); P(>32)~1e-15)
#define OVF_CAP 4096
#define SCALE_F 16777216.0f          // 2^24 fixed-point (order-invariant accumulation)
#define INV_SCALE (1.0 / 16777216.0)

// ---------------- ws layout (4-byte units) ----------------
#define OFF_FLAG   0u                // int[32]: [0]=any-spike flag, [1]=overflow cursor
#define OFF_CNT    32u               // int[N]: per-post firing-edge counts
#define OFF_BITS   100032u           // uint[N_SRC]
#define OFF_BUCKET 117536u           // int[N][BW] = 3.2M (rows 128B-aligned)
#define OFF_OVF    3317536u          // int2[OVF_CAP]
#define OFF_PAYN   3325728u          // int[8*E_EXT]: {mask,q0,q1,q2}{q3,q4,0,0} (firing edges only)
#define OFF_ZBUF   9725728u          // float[5N]  (fallback only)
#define OFF_V      10225728u
#define OFF_R      10325728u
#define OFF_ASC    10425728u         // float[2N]
#define OFF_PR     10625728u         // float[5N]
#define OFF_PC     11125728u         // float[5N]
#define OFF_INPI   11625728u         // int[5N]
// ends 12,125,728 units = 48.5 MB (ws >= 72 MB proven round 3)

// Fused: zero {flag, ovf cursor, cnt} + build 20-bit spike masks.
__global__ void prep(const float* __restrict__ lgn, const float* __restrict__ bkg,
                     unsigned* __restrict__ bits, int* __restrict__ zp) {
    int tid = blockIdx.x * blockDim.x + threadIdx.x;
    if (tid < 100032) zp[tid] = 0;
    int i = tid - 100032;
    if (i < 0 || i >= N_SRC) return;
    unsigned b = 0;
    if (i < N_LGN) {
#pragma unroll
        for (int t = 0; t < T_STEPS; ++t)
            if (lgn[t * N_LGN + i] != 0.0f) b |= (1u << t);
    } else {
        int j = i - N_LGN;
#pragma unroll
        for (int t = 0; t < T_STEPS; ++t)
            if (bkg[t * N_BKG + j] != 0.0f) b |= (1u << t);
    }
    bits[i] = b;
}

// Edge-parallel: quantized 32B record (firing edges only) + direct bucket insert.
// No prefix-scan needed: rank = atomicAdd; bucket partition may vary across
// replays but int accumulation makes the final sums order/partition-invariant.
__global__ void pack_nat(const int* __restrict__ lgn_idx, const float* __restrict__ lgn_w,
                         const float* __restrict__ lgn_fac,
                         const int* __restrict__ bkg_idx, const float* __restrict__ bkg_w,
                         const float* __restrict__ bkg_fac,
                         const unsigned* __restrict__ bits,
                         int* __restrict__ cnt, int* __restrict__ bucket,
                         int2* __restrict__ ovf, int* __restrict__ flag,
                         int* __restrict__ payn) {
    int e = blockIdx.x * blockDim.x + threadIdx.x;
    if (e >= E_EXT) return;
    int post, srow; float w; const float* f;
    if (e < E_LGN) {
        int2 pc2 = ((const int2*)lgn_idx)[e];
        post = pc2.x; srow = pc2.y;
        w = lgn_w[e]; f = lgn_fac + 5 * (size_t)e;
    } else {
        int b = e - E_LGN;
        int2 pc2 = ((const int2*)bkg_idx)[b];
        post = pc2.x; srow = N_LGN + pc2.y;
        w = bkg_w[b]; f = bkg_fac + 5 * (size_t)b;
    }
    unsigned m = bits[srow];          // random read over 70KB: L2-resident
    if (!m) return;                   // never fires: no record, no bucket entry
    float wsc = w * SCALE_F;
    int4 a, b4;
    a.x = (int)m;
    a.y = __float2int_rn(wsc * f[0]);
    a.z = __float2int_rn(wsc * f[1]);
    a.w = __float2int_rn(wsc * f[2]);
    b4.x = __float2int_rn(wsc * f[3]);
    b4.y = __float2int_rn(wsc * f[4]);
    b4.z = 0; b4.w = 0;
    int4* d = (int4*)(payn + 8 * (size_t)e);
    d[0] = a;
    d[1] = b4;
    int rank = atomicAdd(&cnt[post], 1);
    if (rank < BW) {
        bucket[post * BW + rank] = e;
    } else {
        int c = atomicAdd(&flag[1], 1);
        if (c < OVF_CAP) ovf[c] = make_int2(post, e);
    }
}

// Block-cooperative gather into LDS + per-neuron 20-step GLIF scan.
// 256 threads <-> 64 neurons (4 threads/neuron walk its bucket).
__global__ void __launch_bounds__(256) fused_scan(
    const int* __restrict__ cnt, const int* __restrict__ bucket,
    const int2* __restrict__ ovf, const int* __restrict__ payn,
    const float* __restrict__ decay, const float* __restrict__ cf,
    const float* __restrict__ vres, const float* __restrict__ tref,
    const float* __restrict__ kk, const float* __restrict__ aamps,
    const float* __restrict__ vth, const float* __restrict__ norm,
    const float* __restrict__ gg, const float* __restrict__ sdec,
    const float* __restrict__ psci,
    float* __restrict__ out, int* __restrict__ flag)
{
    __shared__ int accs[NN_PER_BLK * ACC_STRIDE];
    int tid = threadIdx.x;
    int n0 = blockIdx.x * NN_PER_BLK;

    for (int i = tid; i < NN_PER_BLK * ACC_STRIDE; i += 256) accs[i] = 0;
    __syncthreads();

    int ln = tid >> 2, l4 = tid & 3;
    int n = n0 + ln;
    if (n < N_NEURONS) {
        int c = cnt[n];
        int cb = (c < BW) ? c : BW;
        int* acc = &accs[ln * ACC_STRIDE];
        for (int k = l4; k < cb; k += 4) {
            int e = bucket[n * BW + k];
            const int4* P = (const int4*)(payn + 8 * (size_t)e);
            int4 a = P[0];
            int4 b = P[1];
            unsigned m = (unsigned)a.x;
            while (m) {
                int t = __ffs(m) - 1;
                m &= m - 1;
                atomicAdd(&acc[t * 5 + 0], a.y);
                atomicAdd(&acc[t * 5 + 1], a.z);
                atomicAdd(&acc[t * 5 + 2], a.w);
                atomicAdd(&acc[t * 5 + 3], b.x);
                atomicAdd(&acc[t * 5 + 4], b.y);
            }
        }
        if (c > BW && l4 == 0) {            // ~never taken
            int oc = flag[1]; if (oc > OVF_CAP) oc = OVF_CAP;
            for (int i = 0; i < oc; ++i) {
                int2 o = ovf[i];
                if (o.x != n) continue;
                const int4* P = (const int4*)(payn + 8 * (size_t)o.y);
                int4 a = P[0]; int4 b = P[1];
                unsigned m = (unsigned)a.x;
                while (m) {
                    int t = __ffs(m) - 1;
                    m &= m - 1;
                    atomicAdd(&acc[t * 5 + 0], a.y);
                    atomicAdd(&acc[t * 5 + 1], a.z);
                    atomicAdd(&acc[t * 5 + 2], a.w);
                    atomicAdd(&acc[t * 5 + 3], b.x);
                    atomicAdd(&acc[t * 5 + 4], b.y);
                }
            }
        }
    }
    __syncthreads();

    if (tid >= NN_PER_BLK) return;
    n = n0 + tid;
    if (n >= N_NEURONS) return;
    const int* acc = &accs[tid * ACC_STRIDE];

    float dec = decay[n], cfa = cf[n], vr = vres[n], tr = tref[n];
    float ek0 = expf(-DT * kk[2 * n]), ek1 = expf(-DT * kk[2 * n + 1]);
    float aa0 = aamps[2 * n], aa1 = aamps[2 * n + 1];
    float vt = vth[n], nm = norm[n], g = gg[n];
    float sd0 = sdec[0], sd1 = sdec[1], sd2 = sdec[2], sd3 = sdec[3], sd4 = sdec[4];
    float pi0 = psci[0], pi1 = psci[1], pi2 = psci[2], pi3 = psci[3], pi4 = psci[4];

    float pr0 = 0.f, pr1 = 0.f, pr2 = 0.f, pr3 = 0.f, pr4 = 0.f;
    float pc0 = 0.f, pc1 = 0.f, pc2 = 0.f, pc3 = 0.f, pc4 = 0.f;
    float v = 0.f, r = 0.f, a0 = 0.f, a1 = 0.f, pz = 0.f;
    bool anyf = false;

#pragma unroll
    for (int t = 0; t < T_STEPS; ++t) {
        float ic = pc0 + pc1 + pc2 + pc3 + pc4;      // input_current uses OLD psc
        float c1 = ic + a0 + a1 + g;
        float dv = dec * v + cfa * c1;
        float nv = (pz > 0.5f) ? vr : dv;
        float nr = r + pz * tr - DT;
        nr = fminf(fmaxf(nr, 0.0f), tr);
        a0 = ek0 * a0 + pz * aa0;
        a1 = ek1 * a1 + pz * aa1;

        float i0 = (float)((double)acc[t * 5 + 0] * INV_SCALE);
        float i1 = (float)((double)acc[t * 5 + 1] * INV_SCALE);
        float i2 = (float)((double)acc[t * 5 + 2] * INV_SCALE);
        float i3 = (float)((double)acc[t * 5 + 3] * INV_SCALE);
        float i4 = (float)((double)acc[t * 5 + 4] * INV_SCALE);

        float np0 = pc0 * sd0 + DT * sd0 * pr0;      // new psc from OLD psc_rise
        float np1 = pc1 * sd1 + DT * sd1 * pr1;
        float np2 = pc2 * sd2 + DT * sd2 * pr2;
        float np3 = pc3 * sd3 + DT * sd3 * pr3;
        float np4 = pc4 * sd4 + DT * sd4 * pr4;
        pr0 = pr0 * sd0 + i0 * pi0;  pc0 = np0;
        pr1 = pr1 * sd1 + i1 * pi1;  pc1 = np1;
        pr2 = pr2 * sd2 + i2 * pi2;  pc2 = np2;
        pr3 = pr3 * sd3 + i3 * pi3;  pc3 = np3;
        pr4 = pr4 * sd4 + i4 * pi4;  pc4 = np4;

        v = nv; r = nr;
        float vsc = (nv - vt) / nm;
        float z = (vsc > 0.0f) ? 1.0f : 0.0f;
        float nz = (nr > 0.0f) ? 0.0f : z;
        out[(size_t)t * N_NEURONS + n] = nz;
        pz = nz;
        anyf = anyf || (nz != 0.0f);
    }
    if (anyf) atomicAdd(flag, 1);
}

// Exact coupled redo inside ONE workgroup; early-exits if no spike detected.
__global__ void __launch_bounds__(1024) fallback_redo(
    const int* __restrict__ cnt, const int* __restrict__ bucket,
    const int2* __restrict__ ovf, const int* __restrict__ payn,
    const int* __restrict__ rec_idx, const float* __restrict__ rec_w,
    const float* __restrict__ rec_fac,
    const float* __restrict__ decay, const float* __restrict__ cf,
    const float* __restrict__ vres, const float* __restrict__ tref,
    const float* __restrict__ kk, const float* __restrict__ aamps,
    const float* __restrict__ vth, const float* __restrict__ norm,
    const float* __restrict__ gg, const float* __restrict__ sdec,
    const float* __restrict__ psci,
    float* __restrict__ zbuf, float* __restrict__ vv, float* __restrict__ rr,
    float* __restrict__ asc, float* __restrict__ pra, float* __restrict__ pca,
    int* __restrict__ inpi, float* __restrict__ out, const int* __restrict__ flag)
{
    if (flag[0] == 0) return;
    int tid = threadIdx.x;
    for (int i = tid; i < N_NEURONS; i += 1024) { vv[i] = 0.f; rr[i] = 0.f; }
    for (int i = tid; i < 2 * N_NEURONS; i += 1024) asc[i] = 0.f;
    for (int i = tid; i < NSYN * N_NEURONS; i += 1024) { pra[i] = 0.f; pca[i] = 0.f; }
    for (int i = tid; i < MAX_DELAY * N_NEURONS; i += 1024) zbuf[i] = 0.f;
    __syncthreads();

    for (int t = 0; t < T_STEPS; ++t) {
        for (int i = tid; i < NSYN * N_NEURONS; i += 1024) inpi[i] = 0;
        __syncthreads();
        for (int n = tid; n < N_NEURONS; n += 1024) {
            int q0 = 0, q1 = 0, q2 = 0, q3 = 0, q4 = 0;
            int c = cnt[n];
            int cb = (c < BW) ? c : BW;
            for (int k = 0; k < cb; ++k) {
                int e = bucket[n * BW + k];
                const int4* P = (const int4*)(payn + 8 * (size_t)e);
                int4 a = P[0]; int4 b = P[1];
                if (((unsigned)a.x >> t) & 1u) {
                    q0 += a.y; q1 += a.z; q2 += a.w; q3 += b.x; q4 += b.y;
                }
            }
            if (c > BW) {
                int oc = flag[1]; if (oc > OVF_CAP) oc = OVF_CAP;
                for (int i = 0; i < oc; ++i) {
                    int2 o = ovf[i];
                    if (o.x != n) continue;
                    const int4* P = (const int4*)(payn + 8 * (size_t)o.y);
                    int4 a = P[0]; int4 b = P[1];
                    if (((unsigned)a.x >> t) & 1u) {
                        q0 += a.y; q1 += a.z; q2 += a.w; q3 += b.x; q4 += b.y;
                    }
                }
            }
            inpi[n * NSYN + 0] = q0; inpi[n * NSYN + 1] = q1; inpi[n * NSYN + 2] = q2;
            inpi[n * NSYN + 3] = q3; inpi[n * NSYN + 4] = q4;
        }
        __syncthreads();
        if (t > 0) {
            for (int e = tid; e < E_REC; e += 1024) {
                int2 pcol = ((const int2*)rec_idx)[e];
                int post = pcol.x, col = pcol.y;
                int d1 = col / N_NEURONS;
                int pre = col - d1 * N_NEURONS;
                int st = t - 1 - d1;
                if (st < 0) continue;
                if (zbuf[(st % MAX_DELAY) * N_NEURONS + pre] != 0.0f) {
                    float w = rec_w[e];
                    atomicAdd(&inpi[post * NSYN + 0], __float2int_rn(w * rec_fac[5 * e + 0] * SCALE_F));
                    atomicAdd(&inpi[post * NSYN + 1], __float2int_rn(w * rec_fac[5 * e + 1] * SCALE_F));
                    atomicAdd(&inpi[post * NSYN + 2], __float2int_rn(w * rec_fac[5 * e + 2] * SCALE_F));
                    atomicAdd(&inpi[post * NSYN + 3], __float2int_rn(w * rec_fac[5 * e + 3] * SCALE_F));
                    atomicAdd(&inpi[post * NSYN + 4], __float2int_rn(w * rec_fac[5 * e + 4] * SCALE_F));
                }
            }
        }
        __syncthreads();
        for (int n = tid; n < N_NEURONS; n += 1024) {
            float pz = (t == 0) ? 0.f : zbuf[((t - 1) % MAX_DELAY) * N_NEURONS + n];
            float prx[NSYN], pcx[NSYN];
            float ic = 0.f;
#pragma unroll
            for (int s = 0; s < NSYN; ++s) {
                prx[s] = pra[n * NSYN + s];
                pcx[s] = pca[n * NSYN + s];
                ic += pcx[s];
            }
            float a0 = asc[2 * n], a1 = asc[2 * n + 1];
            float c1 = ic + a0 + a1 + gg[n];
            float dv = decay[n] * vv[n] + cf[n] * c1;
            float nv = (pz > 0.5f) ? vres[n] : dv;
            float tr = tref[n];
            float nr = rr[n] + pz * tr - DT;
            nr = fminf(fmaxf(nr, 0.0f), tr);
            asc[2 * n]     = expf(-DT * kk[2 * n])     * a0 + pz * aamps[2 * n];
            asc[2 * n + 1] = expf(-DT * kk[2 * n + 1]) * a1 + pz * aamps[2 * n + 1];
#pragma unroll
            for (int s = 0; s < NSYN; ++s) {
                float is = (float)((double)inpi[n * NSYN + s] * INV_SCALE);
                float sd = sdec[s];
                float np = pcx[s] * sd + DT * sd * prx[s];
                pra[n * NSYN + s] = prx[s] * sd + is * psci[s];
                pca[n * NSYN + s] = np;
            }
            vv[n] = nv; rr[n] = nr;
            float vsc = (nv - vth[n]) / norm[n];
            float z = (vsc > 0.0f) ? 1.0f : 0.0f;
            float nz = (nr > 0.0f) ? 0.0f : z;
            zbuf[(t % MAX_DELAY) * N_NEURONS + n] = nz;
            out[(size_t)t * N_NEURONS + n] = nz;
        }
        __syncthreads();
    }
}

extern "C" void kernel_launch(void* const* d_in, const int* in_sizes, int n_in,
                              void* d_out, int out_size, void* d_ws, size_t ws_size,
                              hipStream_t stream) {
    const float* lgn_spikes  = (const float*)d_in[0];
    const float* bkg_spikes  = (const float*)d_in[1];
    const int*   rec_indices = (const int*)  d_in[2];
    const float* rec_w       = (const float*)d_in[3];
    const float* rec_factors = (const float*)d_in[4];
    const int*   lgn_indices = (const int*)  d_in[5];
    const float* lgn_w       = (const float*)d_in[6];
    const float* lgn_factors = (const float*)d_in[7];
    const int*   bkg_indices = (const int*)  d_in[8];
    const float* bkg_w       = (const float*)d_in[9];
    const float* bkg_factors = (const float*)d_in[10];
    const float* decay       = (const float*)d_in[11];
    const float* current_factor = (const float*)d_in[12];
    const float* v_reset     = (const float*)d_in[13];
    const float* t_ref       = (const float*)d_in[14];
    const float* k           = (const float*)d_in[15];
    const float* asc_amps    = (const float*)d_in[16];
    const float* v_th        = (const float*)d_in[17];
    const float* normalizer  = (const float*)d_in[18];
    const float* gathered_g  = (const float*)d_in[19];
    const float* syn_decay   = (const float*)d_in[20];
    const float* psc_initial = (const float*)d_in[21];

    float* ws = (float*)d_ws;
    int*      flag   = (int*)(ws + OFF_FLAG);
    int*      cnt    = (int*)(ws + OFF_CNT);
    unsigned* bits   = (unsigned*)(ws + OFF_BITS);
    int*      bucket = (int*)(ws + OFF_BUCKET);
    int2*     ovf    = (int2*)(ws + OFF_OVF);
    int*      payn   = (int*)(ws + OFF_PAYN);
    float*    zbuf   = ws + OFF_ZBUF;
    float*    vv     = ws + OFF_V;
    float*    rr     = ws + OFF_R;
    float*    asc    = ws + OFF_ASC;
    float*    pra    = ws + OFF_PR;
    float*    pca    = ws + OFF_PC;
    int*      inpi   = (int*)(ws + OFF_INPI);
    float*    out    = (float*)d_out;

    prep<<<(100032 + N_SRC + 255) / 256, 256, 0, stream>>>(lgn_spikes, bkg_spikes, bits, flag);
    pack_nat<<<(E_EXT + 255) / 256, 256, 0, stream>>>(
        lgn_indices, lgn_w, lgn_factors, bkg_indices, bkg_w, bkg_factors,
        bits, cnt, bucket, ovf, flag, payn);
    fused_scan<<<NBLK_FUSED, 256, 0, stream>>>(
        cnt, bucket, ovf, payn,
        decay, current_factor, v_reset, t_ref, k, asc_amps,
        v_th, normalizer, gathered_g, syn_decay, psc_initial,
        out, flag);
    fallback_redo<<<1, 1024, 0, stream>>>(
        cnt, bucket, ovf, payn, rec_indices, rec_w, rec_factors,
        decay, current_factor, v_reset, t_ref, k, asc_amps,
        v_th, normalizer, gathered_g, syn_decay, psc_initial,
        zbuf, vv, rr, asc, pra, pca, inpi, out, flag);
}

// Round 8
// 60.751 us; speedup vs baseline: 6.6581x; 1.1220x over previous
//
#include <hip/hip_runtime.h>

#define N_NEURONS 100000
#define MAX_DELAY 5
#define NSYN 5
#define T_STEPS 20
#define N_LGN 17400
#define N_BKG 100
#define N_SRC (N_LGN + N_BKG)        // 17500
#define E_REC 2000000
#define E_LGN 600000
#define E_BKG 200000
#define E_EXT (E_LGN + E_BKG)        // 800000
#define DT 1.0f
#define NN_PER_BLK 64
#define NBLK_FUSED 1563              // ceil(N/64)
#define ACC_STRIDE 101               // 100 + 1 pad
#define BW 16                        // bucket slots/post; firing edges ~Poisson(5.1), P(>16)~2e-5
#define OVF_CAP 4096
#define SCALE_F 16777216.0f          // 2^24 fixed-point (order-invariant accumulation)
#define INV_SCALE (1.0 / 16777216.0)

// ---------------- ws layout (4-byte units) ----------------
// bucket[post][slot] IS the 32B record {mask,q0,q1,q2}{q3,q4,0,0} — no edge-id join.
#define OFF_FLAG   0u                // int[32]: [0]=any-spike flag, [1]=overflow cursor
#define OFF_CNT    32u               // int[N]
#define OFF_BITS   100032u           // uint[N_SRC]
#define OFF_BUCKET 117536u           // int[N][BW][8] = 12.8M units (51.2 MB region, ~16MB written)
#define OFF_OVF    12917536u         // int[OVF_CAP][8]: {post,mask,q0,q1}{q2,q3,q4,0}
#define OFF_ZBUF   12950304u         // float[5N]  (fallback only)
#define OFF_V      13450304u
#define OFF_R      13550304u
#define OFF_ASC    13650304u         // float[2N]
#define OFF_PR     13850304u         // float[5N]
#define OFF_PC     14350304u         // float[5N]
#define OFF_INPI   14850304u         // int[5N]
// ends 15,350,304 units = 61.4 MB (ws >= 72.6 MB proven in round 3)

// Fused: zero {flag, ovf cursor, cnt} + build 20-bit spike masks.
__global__ void prep(const float* __restrict__ lgn, const float* __restrict__ bkg,
                     unsigned* __restrict__ bits, int* __restrict__ zp) {
    int tid = blockIdx.x * blockDim.x + threadIdx.x;
    if (tid < 100032) zp[tid] = 0;
    int i = tid - 100032;
    if (i < 0 || i >= N_SRC) return;
    unsigned b = 0;
    if (i < N_LGN) {
#pragma unroll
        for (int t = 0; t < T_STEPS; ++t)
            if (lgn[t * N_LGN + i] != 0.0f) b |= (1u << t);
    } else {
        int j = i - N_LGN;
#pragma unroll
        for (int t = 0; t < T_STEPS; ++t)
            if (bkg[t * N_BKG + j] != 0.0f) b |= (1u << t);
    }
    bits[i] = b;
}

// Edge-parallel: firing edges write their quantized 32B record DIRECTLY into
// bucket[post][rank]. One scattered 32B-sector write per firing edge (the
// sector was already paid for a 4B entry; now it carries the payload).
// w/fac loads deferred until after the firing test.
__global__ void pack_nat(const int* __restrict__ lgn_idx, const float* __restrict__ lgn_w,
                         const float* __restrict__ lgn_fac,
                         const int* __restrict__ bkg_idx, const float* __restrict__ bkg_w,
                         const float* __restrict__ bkg_fac,
                         const unsigned* __restrict__ bits,
                         int* __restrict__ cnt, int* __restrict__ bucket,
                         int* __restrict__ ovf, int* __restrict__ flag) {
    int e = blockIdx.x * blockDim.x + threadIdx.x;
    if (e >= E_EXT) return;
    int post, srow;
    if (e < E_LGN) {
        int2 pc2 = ((const int2*)lgn_idx)[e];
        post = pc2.x; srow = pc2.y;
    } else {
        int2 pc2 = ((const int2*)bkg_idx)[e - E_LGN];
        post = pc2.x; srow = N_LGN + pc2.y;
    }
    unsigned m = bits[srow];          // random read over 70KB: L2-resident
    if (!m) return;                   // never fires: nothing stored, nothing fetched
    float w; const float* f;
    if (e < E_LGN) {
        w = lgn_w[e]; f = lgn_fac + 5 * (size_t)e;
    } else {
        int b = e - E_LGN;
        w = bkg_w[b]; f = bkg_fac + 5 * (size_t)b;
    }
    float wsc = w * SCALE_F;
    int q0 = __float2int_rn(wsc * f[0]);
    int q1 = __float2int_rn(wsc * f[1]);
    int q2 = __float2int_rn(wsc * f[2]);
    int q3 = __float2int_rn(wsc * f[3]);
    int q4 = __float2int_rn(wsc * f[4]);
    int rank = atomicAdd(&cnt[post], 1);
    if (rank < BW) {
        int4* d = (int4*)(bucket + ((size_t)post * BW + rank) * 8);
        d[0] = make_int4((int)m, q0, q1, q2);
        d[1] = make_int4(q3, q4, 0, 0);
    } else {
        int c = atomicAdd(&flag[1], 1);
        if (c < OVF_CAP) {
            int4* d = (int4*)(ovf + (size_t)c * 8);
            d[0] = make_int4(post, (int)m, q0, q1);
            d[1] = make_int4(q2, q3, q4, 0);
        }
    }
}

// Block-cooperative gather into LDS + per-neuron 20-step GLIF scan.
// 256 threads <-> 64 neurons (4 threads/neuron walk its bucket row, which is
// read SEQUENTIALLY — adjacent neurons' rows are adjacent in memory).
__global__ void __launch_bounds__(256) fused_scan(
    const int* __restrict__ cnt, const int* __restrict__ bucket,
    const int* __restrict__ ovf,
    const float* __restrict__ decay, const float* __restrict__ cf,
    const float* __restrict__ vres, const float* __restrict__ tref,
    const float* __restrict__ kk, const float* __restrict__ aamps,
    const float* __restrict__ vth, const float* __restrict__ norm,
    const float* __restrict__ gg, const float* __restrict__ sdec,
    const float* __restrict__ psci,
    float* __restrict__ out, int* __restrict__ flag)
{
    __shared__ int accs[NN_PER_BLK * ACC_STRIDE];
    int tid = threadIdx.x;
    int n0 = blockIdx.x * NN_PER_BLK;

    for (int i = tid; i < NN_PER_BLK * ACC_STRIDE; i += 256) accs[i] = 0;
    __syncthreads();

    int ln = tid >> 2, l4 = tid & 3;
    int n = n0 + ln;
    if (n < N_NEURONS) {
        int c = cnt[n];
        int cb = (c < BW) ? c : BW;
        int* acc = &accs[ln * ACC_STRIDE];
        for (int k = l4; k < cb; k += 4) {
            const int4* P = (const int4*)(bucket + ((size_t)n * BW + k) * 8);
            int4 a = P[0];
            int4 b = P[1];
            unsigned m = (unsigned)a.x;
            while (m) {
                int t = __ffs(m) - 1;
                m &= m - 1;
                atomicAdd(&acc[t * 5 + 0], a.y);
                atomicAdd(&acc[t * 5 + 1], a.z);
                atomicAdd(&acc[t * 5 + 2], a.w);
                atomicAdd(&acc[t * 5 + 3], b.x);
                atomicAdd(&acc[t * 5 + 4], b.y);
            }
        }
        if (c > BW && l4 == 0) {            // ~2 neurons expected; exactness path
            int oc = flag[1]; if (oc > OVF_CAP) oc = OVF_CAP;
            for (int i = 0; i < oc; ++i) {
                const int4* O = (const int4*)(ovf + (size_t)i * 8);
                int4 a = O[0];
                if (a.x != n) continue;
                int4 b = O[1];
                unsigned m = (unsigned)a.y;
                while (m) {
                    int t = __ffs(m) - 1;
                    m &= m - 1;
                    atomicAdd(&acc[t * 5 + 0], a.z);
                    atomicAdd(&acc[t * 5 + 1], a.w);
                    atomicAdd(&acc[t * 5 + 2], b.x);
                    atomicAdd(&acc[t * 5 + 3], b.y);
                    atomicAdd(&acc[t * 5 + 4], b.z);
                }
            }
        }
    }
    __syncthreads();

    if (tid >= NN_PER_BLK) return;
    n = n0 + tid;
    if (n >= N_NEURONS) return;
    const int* acc = &accs[tid * ACC_STRIDE];

    float dec = decay[n], cfa = cf[n], vr = vres[n], tr = tref[n];
    float ek0 = expf(-DT * kk[2 * n]), ek1 = expf(-DT * kk[2 * n + 1]);
    float aa0 = aamps[2 * n], aa1 = aamps[2 * n + 1];
    float vt = vth[n], nm = norm[n], g = gg[n];
    float sd0 = sdec[0], sd1 = sdec[1], sd2 = sdec[2], sd3 = sdec[3], sd4 = sdec[4];
    float pi0 = psci[0], pi1 = psci[1], pi2 = psci[2], pi3 = psci[3], pi4 = psci[4];

    float pr0 = 0.f, pr1 = 0.f, pr2 = 0.f, pr3 = 0.f, pr4 = 0.f;
    float pc0 = 0.f, pc1 = 0.f, pc2 = 0.f, pc3 = 0.f, pc4 = 0.f;
    float v = 0.f, r = 0.f, a0 = 0.f, a1 = 0.f, pz = 0.f;
    bool anyf = false;

#pragma unroll
    for (int t = 0; t < T_STEPS; ++t) {
        float ic = pc0 + pc1 + pc2 + pc3 + pc4;      // input_current uses OLD psc
        float c1 = ic + a0 + a1 + g;
        float dv = dec * v + cfa * c1;
        float nv = (pz > 0.5f) ? vr : dv;
        float nr = r + pz * tr - DT;
        nr = fminf(fmaxf(nr, 0.0f), tr);
        a0 = ek0 * a0 + pz * aa0;
        a1 = ek1 * a1 + pz * aa1;

        float i0 = (float)((double)acc[t * 5 + 0] * INV_SCALE);
        float i1 = (float)((double)acc[t * 5 + 1] * INV_SCALE);
        float i2 = (float)((double)acc[t * 5 + 2] * INV_SCALE);
        float i3 = (float)((double)acc[t * 5 + 3] * INV_SCALE);
        float i4 = (float)((double)acc[t * 5 + 4] * INV_SCALE);

        float np0 = pc0 * sd0 + DT * sd0 * pr0;      // new psc from OLD psc_rise
        float np1 = pc1 * sd1 + DT * sd1 * pr1;
        float np2 = pc2 * sd2 + DT * sd2 * pr2;
        float np3 = pc3 * sd3 + DT * sd3 * pr3;
        float np4 = pc4 * sd4 + DT * sd4 * pr4;
        pr0 = pr0 * sd0 + i0 * pi0;  pc0 = np0;
        pr1 = pr1 * sd1 + i1 * pi1;  pc1 = np1;
        pr2 = pr2 * sd2 + i2 * pi2;  pc2 = np2;
        pr3 = pr3 * sd3 + i3 * pi3;  pc3 = np3;
        pr4 = pr4 * sd4 + i4 * pi4;  pc4 = np4;

        v = nv; r = nr;
        float vsc = (nv - vt) / nm;
        float z = (vsc > 0.0f) ? 1.0f : 0.0f;
        float nz = (nr > 0.0f) ? 0.0f : z;
        out[(size_t)t * N_NEURONS + n] = nz;
        pz = nz;
        anyf = anyf || (nz != 0.0f);
    }
    if (anyf) atomicAdd(flag, 1);
}

// Exact coupled redo inside ONE workgroup; early-exits if no spike detected.
__global__ void __launch_bounds__(1024) fallback_redo(
    const int* __restrict__ cnt, const int* __restrict__ bucket,
    const int* __restrict__ ovf,
    const int* __restrict__ rec_idx, const float* __restrict__ rec_w,
    const float* __restrict__ rec_fac,
    const float* __restrict__ decay, const float* __restrict__ cf,
    const float* __restrict__ vres, const float* __restrict__ tref,
    const float* __restrict__ kk, const float* __restrict__ aamps,
    const float* __restrict__ vth, const float* __restrict__ norm,
    const float* __restrict__ gg, const float* __restrict__ sdec,
    const float* __restrict__ psci,
    float* __restrict__ zbuf, float* __restrict__ vv, float* __restrict__ rr,
    float* __restrict__ asc, float* __restrict__ pra, float* __restrict__ pca,
    int* __restrict__ inpi, float* __restrict__ out, const int* __restrict__ flag)
{
    if (flag[0] == 0) return;
    int tid = threadIdx.x;
    for (int i = tid; i < N_NEURONS; i += 1024) { vv[i] = 0.f; rr[i] = 0.f; }
    for (int i = tid; i < 2 * N_NEURONS; i += 1024) asc[i] = 0.f;
    for (int i = tid; i < NSYN * N_NEURONS; i += 1024) { pra[i] = 0.f; pca[i] = 0.f; }
    for (int i = tid; i < MAX_DELAY * N_NEURONS; i += 1024) zbuf[i] = 0.f;
    __syncthreads();

    for (int t = 0; t < T_STEPS; ++t) {
        for (int i = tid; i < NSYN * N_NEURONS; i += 1024) inpi[i] = 0;
        __syncthreads();
        for (int n = tid; n < N_NEURONS; n += 1024) {
            int q0 = 0, q1 = 0, q2 = 0, q3 = 0, q4 = 0;
            int c = cnt[n];
            int cb = (c < BW) ? c : BW;
            for (int k = 0; k < cb; ++k) {
                const int4* P = (const int4*)(bucket + ((size_t)n * BW + k) * 8);
                int4 a = P[0]; int4 b = P[1];
                if (((unsigned)a.x >> t) & 1u) {
                    q0 += a.y; q1 += a.z; q2 += a.w; q3 += b.x; q4 += b.y;
                }
            }
            if (c > BW) {
                int oc = flag[1]; if (oc > OVF_CAP) oc = OVF_CAP;
                for (int i = 0; i < oc; ++i) {
                    const int4* O = (const int4*)(ovf + (size_t)i * 8);
                    int4 a = O[0];
                    if (a.x != n) continue;
                    int4 b = O[1];
                    if (((unsigned)a.y >> t) & 1u) {
                        q0 += a.z; q1 += a.w; q2 += b.x; q3 += b.y; q4 += b.z;
                    }
                }
            }
            inpi[n * NSYN + 0] = q0; inpi[n * NSYN + 1] = q1; inpi[n * NSYN + 2] = q2;
            inpi[n * NSYN + 3] = q3; inpi[n * NSYN + 4] = q4;
        }
        __syncthreads();
        if (t > 0) {
            for (int e = tid; e < E_REC; e += 1024) {
                int2 pcol = ((const int2*)rec_idx)[e];
                int post = pcol.x, col = pcol.y;
                int d1 = col / N_NEURONS;
                int pre = col - d1 * N_NEURONS;
                int st = t - 1 - d1;
                if (st < 0) continue;
                if (zbuf[(st % MAX_DELAY) * N_NEURONS + pre] != 0.0f) {
                    float w = rec_w[e];
                    atomicAdd(&inpi[post * NSYN + 0], __float2int_rn(w * rec_fac[5 * e + 0] * SCALE_F));
                    atomicAdd(&inpi[post * NSYN + 1], __float2int_rn(w * rec_fac[5 * e + 1] * SCALE_F));
                    atomicAdd(&inpi[post * NSYN + 2], __float2int_rn(w * rec_fac[5 * e + 2] * SCALE_F));
                    atomicAdd(&inpi[post * NSYN + 3], __float2int_rn(w * rec_fac[5 * e + 3] * SCALE_F));
                    atomicAdd(&inpi[post * NSYN + 4], __float2int_rn(w * rec_fac[5 * e + 4] * SCALE_F));
                }
            }
        }
        __syncthreads();
        for (int n = tid; n < N_NEURONS; n += 1024) {
            float pz = (t == 0) ? 0.f : zbuf[((t - 1) % MAX_DELAY) * N_NEURONS + n];
            float prx[NSYN], pcx[NSYN];
            float ic = 0.f;
#pragma unroll
            for (int s = 0; s < NSYN; ++s) {
                prx[s] = pra[n * NSYN + s];
                pcx[s] = pca[n * NSYN + s];
                ic += pcx[s];
            }
            float a0 = asc[2 * n], a1 = asc[2 * n + 1];
            float c1 = ic + a0 + a1 + gg[n];
            float dv = decay[n] * vv[n] + cf[n] * c1;
            float nv = (pz > 0.5f) ? vres[n] : dv;
            float tr = tref[n];
            float nr = rr[n] + pz * tr - DT;
            nr = fminf(fmaxf(nr, 0.0f), tr);
            asc[2 * n]     = expf(-DT * kk[2 * n])     * a0 + pz * aamps[2 * n];
            asc[2 * n + 1] = expf(-DT * kk[2 * n + 1]) * a1 + pz * aamps[2 * n + 1];
#pragma unroll
            for (int s = 0; s < NSYN; ++s) {
                float is = (float)((double)inpi[n * NSYN + s] * INV_SCALE);
                float sd = sdec[s];
                float np = pcx[s] * sd + DT * sd * prx[s];
                pra[n * NSYN + s] = prx[s] * sd + is * psci[s];
                pca[n * NSYN + s] = np;
            }
            vv[n] = nv; rr[n] = nr;
            float vsc = (nv - vth[n]) / norm[n];
            float z = (vsc > 0.0f) ? 1.0f : 0.0f;
            float nz = (nr > 0.0f) ? 0.0f : z;
            zbuf[(t % MAX_DELAY) * N_NEURONS + n] = nz;
            out[(size_t)t * N_NEURONS + n] = nz;
        }
        __syncthreads();
    }
}

extern "C" void kernel_launch(void* const* d_in, const int* in_sizes, int n_in,
                              void* d_out, int out_size, void* d_ws, size_t ws_size,
                              hipStream_t stream) {
    const float* lgn_spikes  = (const float*)d_in[0];
    const float* bkg_spikes  = (const float*)d_in[1];
    const int*   rec_indices = (const int*)  d_in[2];
    const float* rec_w       = (const float*)d_in[3];
    const float* rec_factors = (const float*)d_in[4];
    const int*   lgn_indices = (const int*)  d_in[5];
    const float* lgn_w       = (const float*)d_in[6];
    const float* lgn_factors = (const float*)d_in[7];
    const int*   bkg_indices = (const int*)  d_in[8];
    const float* bkg_w       = (const float*)d_in[9];
    const float* bkg_factors = (const float*)d_in[10];
    const float* decay       = (const float*)d_in[11];
    const float* current_factor = (const float*)d_in[12];
    const float* v_reset     = (const float*)d_in[13];
    const float* t_ref       = (const float*)d_in[14];
    const float* k           = (const float*)d_in[15];
    const float* asc_amps    = (const float*)d_in[16];
    const float* v_th        = (const float*)d_in[17];
    const float* normalizer  = (const float*)d_in[18];
    const float* gathered_g  = (const float*)d_in[19];
    const float* syn_decay   = (const float*)d_in[20];
    const float* psc_initial = (const float*)d_in[21];

    float* ws = (float*)d_ws;
    int*      flag   = (int*)(ws + OFF_FLAG);
    int*      cnt    = (int*)(ws + OFF_CNT);
    unsigned* bits   = (unsigned*)(ws + OFF_BITS);
    int*      bucket = (int*)(ws + OFF_BUCKET);
    int*      ovf    = (int*)(ws + OFF_OVF);
    float*    zbuf   = ws + OFF_ZBUF;
    float*    vv     = ws + OFF_V;
    float*    rr     = ws + OFF_R;
    float*    asc    = ws + OFF_ASC;
    float*    pra    = ws + OFF_PR;
    float*    pca    = ws + OFF_PC;
    int*      inpi   = (int*)(ws + OFF_INPI);
    float*    out    = (float*)d_out;

    prep<<<(100032 + N_SRC + 255) / 256, 256, 0, stream>>>(lgn_spikes, bkg_spikes, bits, flag);
    pack_nat<<<(E_EXT + 255) / 256, 256, 0, stream>>>(
        lgn_indices, lgn_w, lgn_factors, bkg_indices, bkg_w, bkg_factors,
        bits, cnt, bucket, ovf, flag);
    fused_scan<<<NBLK_FUSED, 256, 0, stream>>>(
        cnt, bucket, ovf,
        decay, current_factor, v_reset, t_ref, k, asc_amps,
        v_th, normalizer, gathered_g, syn_decay, psc_initial,
        out, flag);
    fallback_redo<<<1, 1024, 0, stream>>>(
        cnt, bucket, ovf, rec_indices, rec_w, rec_factors,
        decay, current_factor, v_reset, t_ref, k, asc_amps,
        v_th, normalizer, gathered_g, syn_decay, psc_initial,
        zbuf, vv, rr, asc, pra, pca, inpi, out, flag);
}

// Round 9
// 59.448 us; speedup vs baseline: 6.8041x; 1.0219x over previous
//
#include <hip/hip_runtime.h>

#define N_NEURONS 100000
#define MAX_DELAY 5
#define NSYN 5
#define T_STEPS 20
#define N_LGN 17400
#define N_BKG 100
#define N_SRC (N_LGN + N_BKG)        // 17500
#define E_REC 2000000
#define E_LGN 600000
#define E_BKG 200000
#define E_EXT (E_LGN + E_BKG)        // 800000
#define DT 1.0f
#define NN_PER_BLK 64
#define NBLK_FUSED 1563              // ceil(N/64)
#define NSEG 4                       // sub-segments per block (contention /4)
#define SEGCAP 160                   // firing edges per segment ~Poisson(90); 160 = +7.4 sigma
#define NCNT (NBLK_FUSED * NSEG)     // 6252 counters, 25KB: L2-hot atomic targets
#define ACC_STRIDE 101               // 100 + 1 pad
#define OVF_CAP 4096
#define SCALE_F 16777216.0f          // 2^24 fixed-point (order-invariant accumulation)
#define INV_SCALE (1.0 / 16777216.0)

// ---------------- ws layout (4-byte units) ----------------
// bucket records grouped by CONSUMER BLOCK (64 posts), tagged with post&63:
// {mask,q0,q1,q2}{q3,q4,post_local,0}. Appends cluster on hot lines.
#define OFF_FLAG   0u                // int[32]: [0]=any-spike flag, [1]=ovf cursor
#define OFF_CNT    32u               // int[NCNT] (+pad) -> zeroed with flag
#define OFF_BITS   6336u             // uint[N_SRC]
#define OFF_BUCKET 23872u            // int[NCNT][SEGCAP][8] = 8,002,560 units (32 MB)
#define OFF_OVF    8026432u          // int[OVF_CAP][8]: {post,mask,q0,q1}{q2,q3,q4,0}
#define OFF_ZBUF   8059200u          // float[5N]  (fallback only)
#define OFF_V      8559200u
#define OFF_R      8659200u
#define OFF_ASC    8759200u          // float[2N]
#define OFF_PR     8959200u          // float[5N]
#define OFF_PC     9459200u          // float[5N]
#define OFF_INPI   9959200u          // int[5N]
// ends 10,459,200 units = 41.8 MB (ws >= 72.6 MB proven in round 3)

// Fused: zero {flag, ovf cursor, cnt} + build 20-bit spike masks.
__global__ void prep(const float* __restrict__ lgn, const float* __restrict__ bkg,
                     unsigned* __restrict__ bits, int* __restrict__ zp) {
    int tid = blockIdx.x * blockDim.x + threadIdx.x;
    if (tid < 6336) zp[tid] = 0;
    int i = tid - 6336;
    if (i < 0 || i >= N_SRC) return;
    unsigned b = 0;
    if (i < N_LGN) {
#pragma unroll
        for (int t = 0; t < T_STEPS; ++t)
            if (lgn[t * N_LGN + i] != 0.0f) b |= (1u << t);
    } else {
        int j = i - N_LGN;
#pragma unroll
        for (int t = 0; t < T_STEPS; ++t)
            if (bkg[t * N_BKG + j] != 0.0f) b |= (1u << t);
    }
    bits[i] = b;
}

// Edge-parallel: firing edges append their quantized record to one of the
// owning consumer-block's 4 segments. Counters are L2-hot (25KB); record
// appends cluster on a few lines per segment (write-coalescible).
__global__ void pack_nat(const int* __restrict__ lgn_idx, const float* __restrict__ lgn_w,
                         const float* __restrict__ lgn_fac,
                         const int* __restrict__ bkg_idx, const float* __restrict__ bkg_w,
                         const float* __restrict__ bkg_fac,
                         const unsigned* __restrict__ bits,
                         int* __restrict__ cnt, int* __restrict__ bucket,
                         int* __restrict__ ovf, int* __restrict__ flag) {
    int e = blockIdx.x * blockDim.x + threadIdx.x;
    if (e >= E_EXT) return;
    int post, srow;
    if (e < E_LGN) {
        int2 pc2 = ((const int2*)lgn_idx)[e];
        post = pc2.x; srow = pc2.y;
    } else {
        int2 pc2 = ((const int2*)bkg_idx)[e - E_LGN];
        post = pc2.x; srow = N_LGN + pc2.y;
    }
    unsigned m = bits[srow];          // random read over 70KB: L2/L3-resident
    if (!m) return;                   // never fires: nothing stored
    float w; const float* f;
    if (e < E_LGN) {
        w = lgn_w[e]; f = lgn_fac + 5 * (size_t)e;
    } else {
        int b = e - E_LGN;
        w = bkg_w[b]; f = bkg_fac + 5 * (size_t)b;
    }
    float wsc = w * SCALE_F;
    int q0 = __float2int_rn(wsc * f[0]);
    int q1 = __float2int_rn(wsc * f[1]);
    int q2 = __float2int_rn(wsc * f[2]);
    int q3 = __float2int_rn(wsc * f[3]);
    int q4 = __float2int_rn(wsc * f[4]);
    int blk = post >> 6;
    int seg = blk * NSEG + (threadIdx.x & (NSEG - 1));
    int rank = atomicAdd(&cnt[seg], 1);
    if (rank < SEGCAP) {
        int4* d = (int4*)(bucket + ((size_t)seg * SEGCAP + rank) * 8);
        d[0] = make_int4((int)m, q0, q1, q2);
        d[1] = make_int4(q3, q4, post & 63, 0);
    } else {
        int c = atomicAdd(&flag[1], 1);
        if (c < OVF_CAP) {
            int4* d = (int4*)(ovf + (size_t)c * 8);
            d[0] = make_int4(post, (int)m, q0, q1);
            d[1] = make_int4(q2, q3, q4, 0);
        }
    }
}

// Block-cooperative gather + per-neuron 20-step GLIF scan.
// 256 threads = 4 groups of 64; group g streams segment g SEQUENTIALLY
// (coalesced), LDS-atomics into acc[post_local][t*5+s].
__global__ void __launch_bounds__(256) fused_scan(
    const int* __restrict__ cnt, const int* __restrict__ bucket,
    const int* __restrict__ ovf,
    const float* __restrict__ decay, const float* __restrict__ cf,
    const float* __restrict__ vres, const float* __restrict__ tref,
    const float* __restrict__ kk, const float* __restrict__ aamps,
    const float* __restrict__ vth, const float* __restrict__ norm,
    const float* __restrict__ gg, const float* __restrict__ sdec,
    const float* __restrict__ psci,
    float* __restrict__ out, int* __restrict__ flag)
{
    __shared__ int accs[NN_PER_BLK * ACC_STRIDE];
    __shared__ int cS[NSEG];
    int tid = threadIdx.x;
    int b = blockIdx.x;
    int n0 = b * NN_PER_BLK;

    for (int i = tid; i < NN_PER_BLK * ACC_STRIDE; i += 256) accs[i] = 0;
    if (tid < NSEG) cS[tid] = cnt[b * NSEG + tid];
    __syncthreads();

    int grp = tid >> 6, lane = tid & 63;
    {
        int c = cS[grp];
        int cb = (c < SEGCAP) ? c : SEGCAP;
        const int* segbase = bucket + (size_t)(b * NSEG + grp) * SEGCAP * 8;
        for (int k = lane; k < cb; k += 64) {
            const int4* P = (const int4*)(segbase + (size_t)k * 8);
            int4 a = P[0];
            int4 bb = P[1];
            unsigned m = (unsigned)a.x;
            int* acc = &accs[bb.z * ACC_STRIDE];
            while (m) {
                int t = __ffs(m) - 1;
                m &= m - 1;
                atomicAdd(&acc[t * 5 + 0], a.y);
                atomicAdd(&acc[t * 5 + 1], a.z);
                atomicAdd(&acc[t * 5 + 2], a.w);
                atomicAdd(&acc[t * 5 + 3], bb.x);
                atomicAdd(&acc[t * 5 + 4], bb.y);
            }
        }
    }
    __syncthreads();

    if (cS[0] > SEGCAP || cS[1] > SEGCAP || cS[2] > SEGCAP || cS[3] > SEGCAP) {
        int oc = flag[1]; if (oc > OVF_CAP) oc = OVF_CAP;
        for (int i = tid; i < oc; i += 256) {
            const int4* O = (const int4*)(ovf + (size_t)i * 8);
            int4 a = O[0];
            if ((a.x >> 6) != b) continue;
            int4 bb = O[1];
            unsigned m = (unsigned)a.y;
            int* acc = &accs[(a.x & 63) * ACC_STRIDE];
            while (m) {
                int t = __ffs(m) - 1;
                m &= m - 1;
                atomicAdd(&acc[t * 5 + 0], a.z);
                atomicAdd(&acc[t * 5 + 1], a.w);
                atomicAdd(&acc[t * 5 + 2], bb.x);
                atomicAdd(&acc[t * 5 + 3], bb.y);
                atomicAdd(&acc[t * 5 + 4], bb.z);
            }
        }
        __syncthreads();
    }

    if (tid >= NN_PER_BLK) return;
    int n = n0 + tid;
    if (n >= N_NEURONS) return;
    const int* acc = &accs[tid * ACC_STRIDE];

    float dec = decay[n], cfa = cf[n], vr = vres[n], tr = tref[n];
    float ek0 = expf(-DT * kk[2 * n]), ek1 = expf(-DT * kk[2 * n + 1]);
    float aa0 = aamps[2 * n], aa1 = aamps[2 * n + 1];
    float vt = vth[n], nm = norm[n], g = gg[n];
    float sd0 = sdec[0], sd1 = sdec[1], sd2 = sdec[2], sd3 = sdec[3], sd4 = sdec[4];
    float pi0 = psci[0], pi1 = psci[1], pi2 = psci[2], pi3 = psci[3], pi4 = psci[4];

    float pr0 = 0.f, pr1 = 0.f, pr2 = 0.f, pr3 = 0.f, pr4 = 0.f;
    float pc0 = 0.f, pc1 = 0.f, pc2 = 0.f, pc3 = 0.f, pc4 = 0.f;
    float v = 0.f, r = 0.f, a0 = 0.f, a1 = 0.f, pz = 0.f;
    bool anyf = false;

#pragma unroll
    for (int t = 0; t < T_STEPS; ++t) {
        float ic = pc0 + pc1 + pc2 + pc3 + pc4;      // input_current uses OLD psc
        float c1 = ic + a0 + a1 + g;
        float dv = dec * v + cfa * c1;
        float nv = (pz > 0.5f) ? vr : dv;
        float nr = r + pz * tr - DT;
        nr = fminf(fmaxf(nr, 0.0f), tr);
        a0 = ek0 * a0 + pz * aa0;
        a1 = ek1 * a1 + pz * aa1;

        float i0 = (float)((double)acc[t * 5 + 0] * INV_SCALE);
        float i1 = (float)((double)acc[t * 5 + 1] * INV_SCALE);
        float i2 = (float)((double)acc[t * 5 + 2] * INV_SCALE);
        float i3 = (float)((double)acc[t * 5 + 3] * INV_SCALE);
        float i4 = (float)((double)acc[t * 5 + 4] * INV_SCALE);

        float np0 = pc0 * sd0 + DT * sd0 * pr0;      // new psc from OLD psc_rise
        float np1 = pc1 * sd1 + DT * sd1 * pr1;
        float np2 = pc2 * sd2 + DT * sd2 * pr2;
        float np3 = pc3 * sd3 + DT * sd3 * pr3;
        float np4 = pc4 * sd4 + DT * sd4 * pr4;
        pr0 = pr0 * sd0 + i0 * pi0;  pc0 = np0;
        pr1 = pr1 * sd1 + i1 * pi1;  pc1 = np1;
        pr2 = pr2 * sd2 + i2 * pi2;  pc2 = np2;
        pr3 = pr3 * sd3 + i3 * pi3;  pc3 = np3;
        pr4 = pr4 * sd4 + i4 * pi4;  pc4 = np4;

        v = nv; r = nr;
        float vsc = (nv - vt) / nm;
        float z = (vsc > 0.0f) ? 1.0f : 0.0f;
        float nz = (nr > 0.0f) ? 0.0f : z;
        out[(size_t)t * N_NEURONS + n] = nz;
        pz = nz;
        anyf = anyf || (nz != 0.0f);
    }
    if (anyf) atomicAdd(flag, 1);
}

// Exact coupled redo inside ONE workgroup; early-exits if no spike detected.
__global__ void __launch_bounds__(1024) fallback_redo(
    const int* __restrict__ cnt, const int* __restrict__ bucket,
    const int* __restrict__ ovf,
    const int* __restrict__ rec_idx, const float* __restrict__ rec_w,
    const float* __restrict__ rec_fac,
    const float* __restrict__ decay, const float* __restrict__ cf,
    const float* __restrict__ vres, const float* __restrict__ tref,
    const float* __restrict__ kk, const float* __restrict__ aamps,
    const float* __restrict__ vth, const float* __restrict__ norm,
    const float* __restrict__ gg, const float* __restrict__ sdec,
    const float* __restrict__ psci,
    float* __restrict__ zbuf, float* __restrict__ vv, float* __restrict__ rr,
    float* __restrict__ asc, float* __restrict__ pra, float* __restrict__ pca,
    int* __restrict__ inpi, float* __restrict__ out, const int* __restrict__ flag)
{
    if (flag[0] == 0) return;
    int tid = threadIdx.x;
    for (int i = tid; i < N_NEURONS; i += 1024) { vv[i] = 0.f; rr[i] = 0.f; }
    for (int i = tid; i < 2 * N_NEURONS; i += 1024) asc[i] = 0.f;
    for (int i = tid; i < NSYN * N_NEURONS; i += 1024) { pra[i] = 0.f; pca[i] = 0.f; }
    for (int i = tid; i < MAX_DELAY * N_NEURONS; i += 1024) zbuf[i] = 0.f;
    __syncthreads();

    for (int t = 0; t < T_STEPS; ++t) {
        for (int i = tid; i < NSYN * N_NEURONS; i += 1024) inpi[i] = 0;
        __syncthreads();
        // external input for step t: scan the owning block's 4 segments
        for (int n = tid; n < N_NEURONS; n += 1024) {
            int q0 = 0, q1 = 0, q2 = 0, q3 = 0, q4 = 0;
            int blk = n >> 6, pl = n & 63;
            bool over = false;
            for (int sub = 0; sub < NSEG; ++sub) {
                int c = cnt[blk * NSEG + sub];
                if (c > SEGCAP) { over = true; c = SEGCAP; }
                const int* segbase = bucket + (size_t)(blk * NSEG + sub) * SEGCAP * 8;
                for (int k = 0; k < c; ++k) {
                    const int4* P = (const int4*)(segbase + (size_t)k * 8);
                    int4 a = P[0]; int4 bb = P[1];
                    if (bb.z == pl && (((unsigned)a.x >> t) & 1u)) {
                        q0 += a.y; q1 += a.z; q2 += a.w; q3 += bb.x; q4 += bb.y;
                    }
                }
            }
            if (over) {
                int oc = flag[1]; if (oc > OVF_CAP) oc = OVF_CAP;
                for (int i = 0; i < oc; ++i) {
                    const int4* O = (const int4*)(ovf + (size_t)i * 8);
                    int4 a = O[0];
                    if (a.x != n) continue;
                    int4 bb = O[1];
                    if (((unsigned)a.y >> t) & 1u) {
                        q0 += a.z; q1 += a.w; q2 += bb.x; q3 += bb.y; q4 += bb.z;
                    }
                }
            }
            inpi[n * NSYN + 0] = q0; inpi[n * NSYN + 1] = q1; inpi[n * NSYN + 2] = q2;
            inpi[n * NSYN + 3] = q3; inpi[n * NSYN + 4] = q4;
        }
        __syncthreads();
        if (t > 0) {
            for (int e = tid; e < E_REC; e += 1024) {
                int2 pcol = ((const int2*)rec_idx)[e];
                int post = pcol.x, col = pcol.y;
                int d1 = col / N_NEURONS;
                int pre = col - d1 * N_NEURONS;
                int st = t - 1 - d1;
                if (st < 0) continue;
                if (zbuf[(st % MAX_DELAY) * N_NEURONS + pre] != 0.0f) {
                    float w = rec_w[e];
                    atomicAdd(&inpi[post * NSYN + 0], __float2int_rn(w * rec_fac[5 * e + 0] * SCALE_F));
                    atomicAdd(&inpi[post * NSYN + 1], __float2int_rn(w * rec_fac[5 * e + 1] * SCALE_F));
                    atomicAdd(&inpi[post * NSYN + 2], __float2int_rn(w * rec_fac[5 * e + 2] * SCALE_F));
                    atomicAdd(&inpi[post * NSYN + 3], __float2int_rn(w * rec_fac[5 * e + 3] * SCALE_F));
                    atomicAdd(&inpi[post * NSYN + 4], __float2int_rn(w * rec_fac[5 * e + 4] * SCALE_F));
                }
            }
        }
        __syncthreads();
        for (int n = tid; n < N_NEURONS; n += 1024) {
            float pz = (t == 0) ? 0.f : zbuf[((t - 1) % MAX_DELAY) * N_NEURONS + n];
            float prx[NSYN], pcx[NSYN];
            float ic = 0.f;
#pragma unroll
            for (int s = 0; s < NSYN; ++s) {
                prx[s] = pra[n * NSYN + s];
                pcx[s] = pca[n * NSYN + s];
                ic += pcx[s];
            }
            float a0 = asc[2 * n], a1 = asc[2 * n + 1];
            float c1 = ic + a0 + a1 + gg[n];
            float dv = decay[n] * vv[n] + cf[n] * c1;
            float nv = (pz > 0.5f) ? vres[n] : dv;
            float tr = tref[n];
            float nr = rr[n] + pz * tr - DT;
            nr = fminf(fmaxf(nr, 0.0f), tr);
            asc[2 * n]     = expf(-DT * kk[2 * n])     * a0 + pz * aamps[2 * n];
            asc[2 * n + 1] = expf(-DT * kk[2 * n + 1]) * a1 + pz * aamps[2 * n + 1];
#pragma unroll
            for (int s = 0; s < NSYN; ++s) {
                float is = (float)((double)inpi[n * NSYN + s] * INV_SCALE);
                float sd = sdec[s];
                float np = pcx[s] * sd + DT * sd * prx[s];
                pra[n * NSYN + s] = prx[s] * sd + is * psci[s];
                pca[n * NSYN + s] = np;
            }
            vv[n] = nv; rr[n] = nr;
            float vsc = (nv - vth[n]) / norm[n];
            float z = (vsc > 0.0f) ? 1.0f : 0.0f;
            float nz = (nr > 0.0f) ? 0.0f : z;
            zbuf[(t % MAX_DELAY) * N_NEURONS + n] = nz;
            out[(size_t)t * N_NEURONS + n] = nz;
        }
        __syncthreads();
    }
}

extern "C" void kernel_launch(void* const* d_in, const int* in_sizes, int n_in,
                              void* d_out, int out_size, void* d_ws, size_t ws_size,
                              hipStream_t stream) {
    const float* lgn_spikes  = (const float*)d_in[0];
    const float* bkg_spikes  = (const float*)d_in[1];
    const int*   rec_indices = (const int*)  d_in[2];
    const float* rec_w       = (const float*)d_in[3];
    const float* rec_factors = (const float*)d_in[4];
    const int*   lgn_indices = (const int*)  d_in[5];
    const float* lgn_w       = (const float*)d_in[6];
    const float* lgn_factors = (const float*)d_in[7];
    const int*   bkg_indices = (const int*)  d_in[8];
    const float* bkg_w       = (const float*)d_in[9];
    const float* bkg_factors = (const float*)d_in[10];
    const float* decay       = (const float*)d_in[11];
    const float* current_factor = (const float*)d_in[12];
    const float* v_reset     = (const float*)d_in[13];
    const float* t_ref       = (const float*)d_in[14];
    const float* k           = (const float*)d_in[15];
    const float* asc_amps    = (const float*)d_in[16];
    const float* v_th        = (const float*)d_in[17];
    const float* normalizer  = (const float*)d_in[18];
    const float* gathered_g  = (const float*)d_in[19];
    const float* syn_decay   = (const float*)d_in[20];
    const float* psc_initial = (const float*)d_in[21];

    float* ws = (float*)d_ws;
    int*      flag   = (int*)(ws + OFF_FLAG);
    int*      cnt    = (int*)(ws + OFF_CNT);
    unsigned* bits   = (unsigned*)(ws + OFF_BITS);
    int*      bucket = (int*)(ws + OFF_BUCKET);
    int*      ovf    = (int*)(ws + OFF_OVF);
    float*    zbuf   = ws + OFF_ZBUF;
    float*    vv     = ws + OFF_V;
    float*    rr     = ws + OFF_R;
    float*    asc    = ws + OFF_ASC;
    float*    pra    = ws + OFF_PR;
    float*    pca    = ws + OFF_PC;
    int*      inpi   = (int*)(ws + OFF_INPI);
    float*    out    = (float*)d_out;

    prep<<<(6336 + N_SRC + 255) / 256, 256, 0, stream>>>(lgn_spikes, bkg_spikes, bits, flag);
    pack_nat<<<(E_EXT + 255) / 256, 256, 0, stream>>>(
        lgn_indices, lgn_w, lgn_factors, bkg_indices, bkg_w, bkg_factors,
        bits, cnt, bucket, ovf, flag);
    fused_scan<<<NBLK_FUSED, 256, 0, stream>>>(
        cnt, bucket, ovf,
        decay, current_factor, v_reset, t_ref, k, asc_amps,
        v_th, normalizer, gathered_g, syn_decay, psc_initial,
        out, flag);
    fallback_redo<<<1, 1024, 0, stream>>>(
        cnt, bucket, ovf, rec_indices, rec_w, rec_factors,
        decay, current_factor, v_reset, t_ref, k, asc_amps,
        v_th, normalizer, gathered_g, syn_decay, psc_initial,
        zbuf, vv, rr, asc, pra, pca, inpi, out, flag);
}